// Round 14
// baseline (1512.031 us; speedup 1.0000x reference)
//
#include <hip/hip_runtime.h>
#include <hip/hip_bf16.h>

typedef __attribute__((ext_vector_type(4))) float f32x4;
typedef __attribute__((ext_vector_type(8))) short short8;
typedef __attribute__((ext_vector_type(4))) int i32x4;
typedef __attribute__((ext_vector_type(2))) unsigned int u32x2;
typedef __attribute__((ext_vector_type(4))) unsigned short u16x4;

static __device__ __forceinline__ unsigned short f2bf(float f) {
  unsigned u = __builtin_bit_cast(unsigned, f);
  u = u + 0x7FFFu + ((u >> 16) & 1u);   // RNE
  return (unsigned short)(u >> 16);
}
static __device__ __forceinline__ float bf2f(unsigned short b) {
  unsigned u = ((unsigned)b) << 16;
  return __builtin_bit_cast(float, u);
}
static __device__ __forceinline__ float sigmoidf_fast(float x) {
  return __builtin_amdgcn_rcpf(1.f + __expf(-x));
}
// packed bf16 pair: low16 = bf16(a), high16 = bf16(b)
static __device__ __forceinline__ unsigned cvt_pk_bf16(float a, float b) {
  unsigned d;
  asm volatile("v_cvt_pk_bf16_f32 %0, %1, %2" : "=v"(d) : "v"(a), "v"(b));
  return d;
}
// Row-wise (16-lane DPP row) inclusive sum; total lands in lane (lane&15)==15.
static __device__ __forceinline__ float row_sum16(float v) {
  int x;
  x = __builtin_amdgcn_update_dpp(0, __builtin_bit_cast(int, v), 0x111, 0xF, 0xF, true);
  v += __builtin_bit_cast(float, x);   // row_shr:1
  x = __builtin_amdgcn_update_dpp(0, __builtin_bit_cast(int, v), 0x112, 0xF, 0xF, true);
  v += __builtin_bit_cast(float, x);   // row_shr:2
  x = __builtin_amdgcn_update_dpp(0, __builtin_bit_cast(int, v), 0x114, 0xF, 0xF, true);
  v += __builtin_bit_cast(float, x);   // row_shr:4
  x = __builtin_amdgcn_update_dpp(0, __builtin_bit_cast(int, v), 0x118, 0xF, 0xF, true);
  v += __builtin_bit_cast(float, x);   // row_shr:8
  return v;
}

// ---------------- cast f32 -> hi/lo bf16 pair (RNE hi) ----------------
__global__ void cast_split_kernel(const float* __restrict__ in,
                                  unsigned short* __restrict__ oh,
                                  unsigned short* __restrict__ ol, int n4) {
  int i = blockIdx.x * blockDim.x + threadIdx.x;
  if (i >= n4) return;
  f32x4 v = ((const f32x4*)in)[i];
  u16x4 h, l;
#pragma unroll
  for (int j = 0; j < 4; ++j) {
    unsigned short hb = f2bf(v[j]);
    h[j] = hb;
    l[j] = f2bf(v[j] - bf2f(hb));
  }
  ((u16x4*)oh)[i] = h;
  ((u16x4*)ol)[i] = l;
}

// ---------------- transpose + cast: (R,C) f32 -> (C,R) bf16 ----------------
__global__ void tcast_kernel(const float* __restrict__ in,
                             unsigned short* __restrict__ out, int R, int C) {
  int i = blockIdx.x * blockDim.x + threadIdx.x;
  if (i >= R * C) return;
  int r = i / C, c = i % C;
  out[(size_t)c * R + r] = f2bf(in[i]);
}

// ---------------- transpose + split cast: (R,C) f32 -> (C,R) hi/lo bf16 ----------------
__global__ void tcast_split_kernel(const float* __restrict__ in,
                                   unsigned short* __restrict__ oh,
                                   unsigned short* __restrict__ ol, int R, int C) {
  int i = blockIdx.x * blockDim.x + threadIdx.x;
  if (i >= R * C) return;
  int r = i / C, c = i % C;
  float v = in[i];
  unsigned short hb = f2bf(v);
  oh[(size_t)c * R + r] = hb;
  ol[(size_t)c * R + r] = f2bf(v - bf2f(hb));
}

// ---------------- f gate: one wave per token row (pure f32) ----------------
__global__ __launch_bounds__(256) void fgate_kernel(const float* __restrict__ x,
                                                    const float* __restrict__ Wf,
                                                    const float* __restrict__ bfv,
                                                    float* __restrict__ fbuf) {
  int wid = (blockIdx.x * blockDim.x + threadIdx.x) >> 6;  // token row 0..4095
  int lane = threadIdx.x & 63;
  const float* xr = x + (size_t)wid * 1024;
  float acc[8] = {0.f, 0.f, 0.f, 0.f, 0.f, 0.f, 0.f, 0.f};
#pragma unroll 4
  for (int it = 0; it < 16; ++it) {
    int d = it * 64 + lane;
    float xv = xr[d];
    f32x4 w0 = *(const f32x4*)(Wf + (size_t)d * 8);
    f32x4 w1 = *(const f32x4*)(Wf + (size_t)d * 8 + 4);
    acc[0] += xv * w0[0]; acc[1] += xv * w0[1];
    acc[2] += xv * w0[2]; acc[3] += xv * w0[3];
    acc[4] += xv * w1[0]; acc[5] += xv * w1[1];
    acc[6] += xv * w1[2]; acc[7] += xv * w1[3];
  }
#pragma unroll
  for (int n = 0; n < 8; ++n) {
#pragma unroll
    for (int m = 1; m < 64; m <<= 1) acc[n] += __shfl_xor(acc[n], m, 64);
  }
  if (lane == 0) {
#pragma unroll
    for (int n = 0; n < 8; ++n)
      fbuf[(size_t)wid * 8 + n] = sigmoidf_fast(acc[n] + bfv[n]);
  }
}

// ---------------- causal depthwise conv (KC=4) + SiLU, all 3 tensors ----------------
__global__ void conv_silu_kernel(const float* __restrict__ pre,
                                 const float* __restrict__ cwq,
                                 const float* __restrict__ cwk,
                                 const float* __restrict__ cwv,
                                 float* __restrict__ outb) {
  int i = blockIdx.x * blockDim.x + threadIdx.x;  // B*L*512
  int which = blockIdx.y;
  const float* cw = (which == 0) ? cwq : (which == 1) ? cwk : cwv;
  const float* p = pre + (size_t)which * 2097152 + i;
  int c = i & 511;
  int l = (i >> 9) & 1023;
  float w0 = cw[c * 4 + 0], w1 = cw[c * 4 + 1], w2 = cw[c * 4 + 2], w3 = cw[c * 4 + 3];
  float acc = w3 * p[0];
  if (l >= 1) acc += w2 * p[-512];
  if (l >= 2) acc += w1 * p[-1024];
  if (l >= 3) acc += w0 * p[-1536];
  outb[(size_t)which * 2097152 + i] = acc * sigmoidf_fast(acc);
}

// ---------------- plain bf16 MFMA GEMM: C(M,Nd) = A * Bt^T ----------------
__global__ __launch_bounds__(256) void gemm_bf16_kernel(
    const unsigned short* __restrict__ A, const unsigned short* __restrict__ Bt,
    float* __restrict__ C, int Kd, int Nd, size_t BtStride, size_t CStride) {
  __shared__ unsigned short Ash[128][40];
  __shared__ unsigned short Bsh[128][40];
  const int tid = threadIdx.x;
  const int wave = tid >> 6, lane = tid & 63;
  const int g = lane >> 4, lr = lane & 15;
  const int m0 = blockIdx.x * 128, n0 = blockIdx.y * 128;
  const unsigned short* Bz = Bt + blockIdx.z * BtStride;
  float* Cz = C + blockIdx.z * CStride;
  const int wm = (wave >> 1) * 64, wn = (wave & 1) * 64;

  f32x4 acc[4][4];
#pragma unroll
  for (int a = 0; a < 4; ++a)
#pragma unroll
    for (int bq = 0; bq < 4; ++bq) acc[a][bq] = (f32x4){0.f, 0.f, 0.f, 0.f};

  for (int k0 = 0; k0 < Kd; k0 += 32) {
#pragma unroll
    for (int it = 0; it < 2; ++it) {
      int cch = tid + 256 * it;
      int r = cch >> 2, cc = cch & 3;
      *(i32x4*)&Ash[r][cc * 8] = *(const i32x4*)(A + (size_t)(m0 + r) * Kd + k0 + cc * 8);
      *(i32x4*)&Bsh[r][cc * 8] = *(const i32x4*)(Bz + (size_t)(n0 + r) * Kd + k0 + cc * 8);
    }
    __syncthreads();
    short8 af[4], bfr[4];
#pragma unroll
    for (int mt = 0; mt < 4; ++mt) af[mt] = *(const short8*)&Ash[wm + mt * 16 + lr][g * 8];
#pragma unroll
    for (int nt = 0; nt < 4; ++nt) bfr[nt] = *(const short8*)&Bsh[wn + nt * 16 + lr][g * 8];
#pragma unroll
    for (int mt = 0; mt < 4; ++mt)
#pragma unroll
      for (int nt = 0; nt < 4; ++nt)
        acc[mt][nt] = __builtin_amdgcn_mfma_f32_16x16x32_bf16(af[mt], bfr[nt], acc[mt][nt], 0, 0, 0);
    __syncthreads();
  }
#pragma unroll
  for (int mt = 0; mt < 4; ++mt)
#pragma unroll
    for (int nt = 0; nt < 4; ++nt)
#pragma unroll
      for (int r = 0; r < 4; ++r) {
        int m = m0 + wm + mt * 16 + g * 4 + r;
        int n = n0 + wn + nt * 16 + lr;
        Cz[(size_t)m * Nd + n] = acc[mt][nt][r];
      }
}

// ---------------- split-bf16 (3-term f32-emulation) GEMM ----------------
__global__ __launch_bounds__(256) void gemm_split_kernel(
    const unsigned short* __restrict__ Ah, const unsigned short* __restrict__ Al,
    const unsigned short* __restrict__ Bth, const unsigned short* __restrict__ Btl,
    float* __restrict__ C, int Kd, int Nd, size_t BtStride, size_t CStride) {
  __shared__ unsigned short AshH[128][40];
  __shared__ unsigned short AshL[128][40];
  __shared__ unsigned short BshH[128][40];
  __shared__ unsigned short BshL[128][40];
  const int tid = threadIdx.x;
  const int wave = tid >> 6, lane = tid & 63;
  const int g = lane >> 4, lr = lane & 15;
  const int m0 = blockIdx.x * 128, n0 = blockIdx.y * 128;
  const unsigned short* Bzh = Bth + blockIdx.z * BtStride;
  const unsigned short* Bzl = Btl + blockIdx.z * BtStride;
  float* Cz = C + blockIdx.z * CStride;
  const int wm = (wave >> 1) * 64, wn = (wave & 1) * 64;

  f32x4 acc[4][4];
#pragma unroll
  for (int a = 0; a < 4; ++a)
#pragma unroll
    for (int bq = 0; bq < 4; ++bq) acc[a][bq] = (f32x4){0.f, 0.f, 0.f, 0.f};

  for (int k0 = 0; k0 < Kd; k0 += 32) {
#pragma unroll
    for (int it = 0; it < 2; ++it) {
      int cch = tid + 256 * it;
      int r = cch >> 2, cc = cch & 3;
      size_t ao = (size_t)(m0 + r) * Kd + k0 + cc * 8;
      size_t bo = (size_t)(n0 + r) * Kd + k0 + cc * 8;
      *(i32x4*)&AshH[r][cc * 8] = *(const i32x4*)(Ah + ao);
      *(i32x4*)&AshL[r][cc * 8] = *(const i32x4*)(Al + ao);
      *(i32x4*)&BshH[r][cc * 8] = *(const i32x4*)(Bzh + bo);
      *(i32x4*)&BshL[r][cc * 8] = *(const i32x4*)(Bzl + bo);
    }
    __syncthreads();
    short8 afh[4], afl[4], bfh[4], bfl[4];
#pragma unroll
    for (int mt = 0; mt < 4; ++mt) {
      afh[mt] = *(const short8*)&AshH[wm + mt * 16 + lr][g * 8];
      afl[mt] = *(const short8*)&AshL[wm + mt * 16 + lr][g * 8];
    }
#pragma unroll
    for (int nt = 0; nt < 4; ++nt) {
      bfh[nt] = *(const short8*)&BshH[wn + nt * 16 + lr][g * 8];
      bfl[nt] = *(const short8*)&BshL[wn + nt * 16 + lr][g * 8];
    }
#pragma unroll
    for (int mt = 0; mt < 4; ++mt)
#pragma unroll
      for (int nt = 0; nt < 4; ++nt) {
        f32x4 a = acc[mt][nt];
        a = __builtin_amdgcn_mfma_f32_16x16x32_bf16(afl[mt], bfh[nt], a, 0, 0, 0);
        a = __builtin_amdgcn_mfma_f32_16x16x32_bf16(afh[mt], bfl[nt], a, 0, 0, 0);
        a = __builtin_amdgcn_mfma_f32_16x16x32_bf16(afh[mt], bfh[nt], a, 0, 0, 0);
        acc[mt][nt] = a;
      }
    __syncthreads();
  }
#pragma unroll
  for (int mt = 0; mt < 4; ++mt)
#pragma unroll
    for (int nt = 0; nt < 4; ++nt)
#pragma unroll
      for (int r = 0; r < 4; ++r) {
        int m = m0 + wm + mt * 16 + g * 4 + r;
        int n = n0 + wn + nt * 16 + lr;
        Cz[(size_t)m * Nd + n] = acc[mt][nt][r];
      }
}

// ---------------- recurrent scan: 1 WAVE per (chain, k-slice) -- barrier-free ----------------
// Each k-slice (16 rows) of each chain handled by ONE 64-lane wave that owns all
// four 16-w tiles (24 MFMAs, 16 H f32/lane). Every LDS location in the step loop
// (H planes, stage, yst) is written and read by the SAME wave; the DS pipe
// executes a wave's LDS ops in order, so NO __syncthreads anywhere.
// 128 blocks x 64 threads. Layout math = r11-verified with wave -> tile t:
// H planes (ping-pong): row lr at byte lr*128, elem v at (2v) ^ ((lr&7)<<4).
__global__ __launch_bounds__(64) void scan_kernel(
    const float* __restrict__ qbuf, const float* __restrict__ kbuf,
    const float* __restrict__ vbuf, const float* __restrict__ fbuf,
    const float* __restrict__ W, unsigned short* __restrict__ ypart,
    float* __restrict__ Hout) {
  const int lane = threadIdx.x & 63;
  const int g = lane >> 4, lr = lane & 15;
  const int bz = blockIdx.x;
  const int chain = bz >> 2, ks = bz & 3;
  const int b = chain >> 3, n = chain & 7;
  const int swz = (lr & 7) << 4;

  __shared__ unsigned short Hh[2][1024];   // 16x64 bf16 hi, ping-pong
  __shared__ unsigned short Hl[2][1024];   // lo planes
  __shared__ float stage[2][16][192];      // 24 KB
  __shared__ float fs[2][16];
  __shared__ float yst[16][64];            // 4 KB

  // zero plane 0 (H_0 = 0): 512 u32 per plane, 64 lanes x 8
  for (int i = lane; i < 512; i += 64) {
    ((unsigned*)Hh[0])[i] = 0u;
    ((unsigned*)Hl[0])[i] = 0u;
  }

  // W^T split hi/lo fragments: A[m=w][v-chunk], w = t*16 + lr, t = 0..3
  const float* Wn = W + (size_t)n * 4096;
  short8 Af[4][2], Alw[4][2];
#pragma unroll
  for (int t = 0; t < 4; ++t)
#pragma unroll
    for (int s = 0; s < 2; ++s) {
      int wcol = t * 16 + lr;
      short8 ah, al;
#pragma unroll
      for (int j = 0; j < 8; ++j) {
        float wv = Wn[(size_t)(s * 32 + g * 8 + j) * 64 + wcol];
        unsigned short hb = f2bf(wv);
        ah[j] = (short)hb;
        al[j] = (short)f2bf(wv - bf2f(hb));
      }
      Af[t][s] = ah; Alw[t][s] = al;
    }

  // chunk staging: 16 steps x 192 floats = 768 f32x4, 64 lanes x 12
  auto stage_chunk = [&](int c, int buf) {
#pragma unroll
    for (int i = 0; i < 12; ++i) {
      int fi = lane + i * 64;
      int st = fi / 48, un = fi - st * 48;
      const float* basep = (un < 16) ? qbuf : (un < 32) ? kbuf : vbuf;
      f32x4 val = *(const f32x4*)(basep + (size_t)(b * 1024 + c * 16 + st) * 512 +
                                  n * 64 + (un & 15) * 4);
      *(f32x4*)&stage[buf][st][un * 4] = val;
    }
    if (lane < 16) fs[buf][lane] = fbuf[(size_t)(b * 1024 + c * 16 + lane) * 8 + n];
  };

  f32x4 H[4];   // H[ks*16+lr][w = t*16+4g+r], f32 master
#pragma unroll
  for (int t = 0; t < 4; ++t) H[t] = (f32x4){0.f, 0.f, 0.f, 0.f};
  int sb = 0, pp = 0;

  stage_chunk(0, 0);

  const f32x4 zf = (f32x4){0.f, 0.f, 0.f, 0.f};
  const int bo0 = (16 * g) ^ swz;               // B-frag chunk 0
  const int bo1 = (64 + 16 * g) ^ swz;          // chunk 1
  int wo[4];
#pragma unroll
  for (int t = 0; t < 4; ++t) wo[t] = (32 * t + 8 * g) ^ swz;
  const float K2L2E = 2.885390081777927f;       // 2*log2(e)
  const int kg = ks * 16 + lr;                  // global k row of this lane

  for (int c = 0; c < 64; ++c) {
    if (c < 63) stage_chunk(c + 1, sb ^ 1);
    for (int tl = 0; tl < 16; ++tl) {
      const float* srow = &stage[sb][tl][0];

      // B-frags of H_t slice from plane pp (shared across all 4 tiles)
      const char* hrh = (const char*)(Hh[pp] + lr * 64);
      const char* hrl = (const char*)(Hl[pp] + lr * 64);
      short8 Bh0 = *(const short8*)(hrh + bo0);
      short8 Bh1 = *(const short8*)(hrh + bo1);
      short8 Bl0 = *(const short8*)(hrl + bo0);
      short8 Bl1 = *(const short8*)(hrl + bo1);

      // scalar stage reads early (overlap with MFMAs)
      float kval = srow[64 + kg];
      float fc = fs[sb][tl];
      float qs = srow[kg];
      f32x4 vv[4];
#pragma unroll
      for (int t = 0; t < 4; ++t)
        vv[t] = *(const f32x4*)(srow + 128 + t * 16 + 4 * g);

      // 24 MFMAs: 3-term split, 8 independent chains of 3
      f32x4 cX[4], cY[4];
#pragma unroll
      for (int t = 0; t < 4; ++t) {
        cX[t] = __builtin_amdgcn_mfma_f32_16x16x32_bf16(Alw[t][0], Bh0, zf, 0, 0, 0);
        cY[t] = __builtin_amdgcn_mfma_f32_16x16x32_bf16(Alw[t][1], Bh1, zf, 0, 0, 0);
      }
#pragma unroll
      for (int t = 0; t < 4; ++t) {
        cX[t] = __builtin_amdgcn_mfma_f32_16x16x32_bf16(Af[t][0], Bl0, cX[t], 0, 0, 0);
        cY[t] = __builtin_amdgcn_mfma_f32_16x16x32_bf16(Af[t][1], Bl1, cY[t], 0, 0, 0);
      }
#pragma unroll
      for (int t = 0; t < 4; ++t) {
        cX[t] = __builtin_amdgcn_mfma_f32_16x16x32_bf16(Af[t][0], Bh0, cX[t], 0, 0, 0);
        cY[t] = __builtin_amdgcn_mfma_f32_16x16x32_bf16(Af[t][1], Bh1, cY[t], 0, 0, 0);
      }

      // tanh (exp2-fused) + gate blend -> H_{t+1} (f32, exact)
#pragma unroll
      for (int t = 0; t < 4; ++t) {
        f32x4 a = cX[t] + cY[t];
#pragma unroll
        for (int r = 0; r < 4; ++r) {
          float arg = fmaf(kval, vv[t][r], a[r]);
          float cd = fmaf(-2.f, __builtin_amdgcn_rcpf(1.f + __builtin_amdgcn_exp2f(arg * K2L2E)), 1.f);
          H[t][r] = fmaf(fc, H[t][r] - cd, cd);
        }
      }

      // pack (cvt_pk) and write H_{t+1} to plane pp^1, all tiles
      {
        char* hwh = (char*)(Hh[pp ^ 1] + lr * 64);
        char* hwl = (char*)(Hl[pp ^ 1] + lr * 64);
#pragma unroll
        for (int t = 0; t < 4; ++t) {
          unsigned ph0 = cvt_pk_bf16(H[t][0], H[t][1]);
          unsigned ph1 = cvt_pk_bf16(H[t][2], H[t][3]);
          float r0 = H[t][0] - __builtin_bit_cast(float, ph0 << 16);
          float r1 = H[t][1] - __builtin_bit_cast(float, ph0 & 0xFFFF0000u);
          float r2 = H[t][2] - __builtin_bit_cast(float, ph1 << 16);
          float r3 = H[t][3] - __builtin_bit_cast(float, ph1 & 0xFFFF0000u);
          *(u32x2*)(hwh + wo[t]) = (u32x2){ph0, ph1};
          *(u32x2*)(hwl + wo[t]) = (u32x2){cvt_pk_bf16(r0, r1), cvt_pk_bf16(r2, r3)};
        }
      }

      // y slice-partials (DPP row-sum over the 16 k-lanes; VALU covers writes)
#pragma unroll
      for (int t = 0; t < 4; ++t) {
        float y0 = row_sum16(qs * H[t][0]);
        float y1 = row_sum16(qs * H[t][1]);
        float y2 = row_sum16(qs * H[t][2]);
        float y3 = row_sum16(qs * H[t][3]);
        if (lr == 15)
          *(f32x4*)&yst[tl][t * 16 + 4 * g] = (f32x4){y0, y1, y2, y3};
      }

      pp ^= 1;   // no barrier: same-wave DS ops execute in order
    }

    // flush y slice-partials for this chunk (bf16), 64 lanes x 8 u32
#pragma unroll
    for (int i = 0; i < 8; ++i) {
      int j = i * 64 + lane;           // u32 index into 512 pairs
      int tl2 = j >> 5, w = (j & 31) * 2;
      unsigned val = (unsigned)f2bf(yst[tl2][w]) | ((unsigned)f2bf(yst[tl2][w + 1]) << 16);
      *(unsigned*)(ypart + (size_t)ks * 2097152 +
                   (size_t)(b * 1024 + c * 16 + tl2) * 512 + n * 64 + w) = val;
    }
    sb ^= 1;
  }

  // H_final (f32 master): this slice's rows, all tiles
  float* Ho = Hout + (size_t)(b * 8 + n) * 4096;
#pragma unroll
  for (int t = 0; t < 4; ++t)
    *(f32x4*)&Ho[(size_t)kg * 64 + t * 16 + g * 4] = H[t];
}

// ---------------- sum 4 y slice-partials -> bf16 y ----------------
__global__ void ysum_kernel(const unsigned short* __restrict__ yp,
                            unsigned short* __restrict__ yb) {
  int i = blockIdx.x * 256 + threadIdx.x;   // x4 elems
  u16x4 s0 = ((const u16x4*)yp)[i];
  u16x4 s1 = ((const u16x4*)(yp + 2097152))[i];
  u16x4 s2 = ((const u16x4*)(yp + 2 * 2097152))[i];
  u16x4 s3 = ((const u16x4*)(yp + 3 * 2097152))[i];
  u16x4 o;
#pragma unroll
  for (int j = 0; j < 4; ++j)
    o[j] = f2bf(bf2f(s0[j]) + bf2f(s1[j]) + bf2f(s2[j]) + bf2f(s3[j]));
  ((u16x4*)yb)[i] = o;
}

// ---------------- launch ----------------
extern "C" void kernel_launch(void* const* d_in, const int* in_sizes, int n_in,
                              void* d_out, int out_size, void* d_ws, size_t ws_size,
                              hipStream_t stream) {
  const float* x   = (const float*)d_in[0];
  const float* Wq  = (const float*)d_in[1];
  const float* Wk  = (const float*)d_in[2];
  const float* Wv  = (const float*)d_in[3];
  const float* Wf  = (const float*)d_in[4];
  const float* bfv = (const float*)d_in[5];
  const float* cwq = (const float*)d_in[6];
  const float* cwk = (const float*)d_in[7];
  const float* cwv = (const float*)d_in[8];
  const float* W   = (const float*)d_in[9];
  const float* Wo  = (const float*)d_in[10];
  float* outp = (float*)d_out;

  char* ws = (char*)d_ws;
  size_t off = 0;
  auto alloc = [&](size_t bytes) {
    char* pp = ws + off;
    off = (off + bytes + 255) & ~(size_t)255;
    return pp;
  };
  unsigned short* xbh  = (unsigned short*)alloc((size_t)4194304 * 2);
  unsigned short* xbl  = (unsigned short*)alloc((size_t)4194304 * 2);
  unsigned short* wtbh = (unsigned short*)alloc((size_t)3 * 524288 * 2);
  unsigned short* wtbl = (unsigned short*)alloc((size_t)3 * 524288 * 2);
  float* pre  = (float*)alloc((size_t)3 * 2097152 * 4);   // aliased: y partials
  float* qkv  = (float*)alloc((size_t)3 * 2097152 * 4);
  float* fbuf = (float*)alloc((size_t)32768 * 4);
  unsigned short* yb  = (unsigned short*)alloc((size_t)2097152 * 2);
  unsigned short* wot = (unsigned short*)alloc((size_t)524288 * 2);
  unsigned short* ypart = (unsigned short*)pre;  // pre is dead after conv_silu

  // casts / transposes (split hi/lo for the amplified paths)
  cast_split_kernel<<<4096, 256, 0, stream>>>(x, xbh, xbl, 1048576);
  tcast_split_kernel<<<2048, 256, 0, stream>>>(Wq, wtbh, wtbl, 1024, 512);
  tcast_split_kernel<<<2048, 256, 0, stream>>>(Wk, wtbh + 524288, wtbl + 524288, 1024, 512);
  tcast_split_kernel<<<2048, 256, 0, stream>>>(Wv, wtbh + 2 * 524288, wtbl + 2 * 524288, 1024, 512);
  // gate
  fgate_kernel<<<1024, 256, 0, stream>>>(x, Wf, bfv, fbuf);
  // q pre-activation: plain bf16 (un-amplified path)
  dim3 gq(32, 4, 1);
  gemm_bf16_kernel<<<gq, 256, 0, stream>>>(xbh, wtbh, pre, 1024, 512,
                                           (size_t)0, (size_t)0);
  // k,v pre-activations: split-bf16 (amplified path)
  dim3 gkv(32, 4, 2);
  gemm_split_kernel<<<gkv, 256, 0, stream>>>(xbh, xbl, wtbh + 524288, wtbl + 524288,
                                             pre + 2097152, 1024, 512,
                                             (size_t)524288, (size_t)2097152);
  // conv + silu (all three in one launch); pre is dead afterwards
  dim3 gc(8192, 3, 1);
  conv_silu_kernel<<<gc, 256, 0, stream>>>(pre, cwq, cwk, cwv, qkv);
  // recurrent scan: 128 blocks (32 chains x 4 k-slices) x 64 threads (1 wave)
  scan_kernel<<<128, 64, 0, stream>>>(qkv, qkv + 2097152, qkv + 2 * 2097152, fbuf, W,
                                      ypart, outp + 4194304);
  // fold slice partials -> yb (bf16)
  ysum_kernel<<<2048, 256, 0, stream>>>(ypart, yb);
  // output projection
  tcast_kernel<<<2048, 256, 0, stream>>>(Wo, wot, 512, 1024);
  dim3 g2(32, 8, 1);
  gemm_bf16_kernel<<<g2, 256, 0, stream>>>(yb, wot, outp, 512, 1024, (size_t)0, (size_t)0);
}

// Round 15
// 704.406 us; speedup vs baseline: 2.1465x; 2.1465x over previous
//
#include <hip/hip_runtime.h>
#include <hip/hip_bf16.h>

typedef __attribute__((ext_vector_type(4))) float f32x4;
typedef __attribute__((ext_vector_type(8))) short short8;
typedef __attribute__((ext_vector_type(4))) int i32x4;
typedef __attribute__((ext_vector_type(2))) unsigned int u32x2;
typedef __attribute__((ext_vector_type(4))) unsigned short u16x4;

static __device__ __forceinline__ unsigned short f2bf(float f) {
  unsigned u = __builtin_bit_cast(unsigned, f);
  u = u + 0x7FFFu + ((u >> 16) & 1u);   // RNE
  return (unsigned short)(u >> 16);
}
static __device__ __forceinline__ float bf2f(unsigned short b) {
  unsigned u = ((unsigned)b) << 16;
  return __builtin_bit_cast(float, u);
}
static __device__ __forceinline__ float sigmoidf_fast(float x) {
  return __builtin_amdgcn_rcpf(1.f + __expf(-x));
}
// packed bf16 pair: low16 = bf16(a), high16 = bf16(b)
static __device__ __forceinline__ unsigned cvt_pk_bf16(float a, float b) {
  unsigned d;
  asm volatile("v_cvt_pk_bf16_f32 %0, %1, %2" : "=v"(d) : "v"(a), "v"(b));
  return d;
}
// Row-wise (16-lane DPP row) inclusive sum; total lands in lane (lane&15)==15.
static __device__ __forceinline__ float row_sum16(float v) {
  int x;
  x = __builtin_amdgcn_update_dpp(0, __builtin_bit_cast(int, v), 0x111, 0xF, 0xF, true);
  v += __builtin_bit_cast(float, x);   // row_shr:1
  x = __builtin_amdgcn_update_dpp(0, __builtin_bit_cast(int, v), 0x112, 0xF, 0xF, true);
  v += __builtin_bit_cast(float, x);   // row_shr:2
  x = __builtin_amdgcn_update_dpp(0, __builtin_bit_cast(int, v), 0x114, 0xF, 0xF, true);
  v += __builtin_bit_cast(float, x);   // row_shr:4
  x = __builtin_amdgcn_update_dpp(0, __builtin_bit_cast(int, v), 0x118, 0xF, 0xF, true);
  v += __builtin_bit_cast(float, x);   // row_shr:8
  return v;
}

// ---------------- cast f32 -> hi/lo bf16 pair (RNE hi) ----------------
__global__ void cast_split_kernel(const float* __restrict__ in,
                                  unsigned short* __restrict__ oh,
                                  unsigned short* __restrict__ ol, int n4) {
  int i = blockIdx.x * blockDim.x + threadIdx.x;
  if (i >= n4) return;
  f32x4 v = ((const f32x4*)in)[i];
  u16x4 h, l;
#pragma unroll
  for (int j = 0; j < 4; ++j) {
    unsigned short hb = f2bf(v[j]);
    h[j] = hb;
    l[j] = f2bf(v[j] - bf2f(hb));
  }
  ((u16x4*)oh)[i] = h;
  ((u16x4*)ol)[i] = l;
}

// ---------------- transpose + cast: (R,C) f32 -> (C,R) bf16 ----------------
__global__ void tcast_kernel(const float* __restrict__ in,
                             unsigned short* __restrict__ out, int R, int C) {
  int i = blockIdx.x * blockDim.x + threadIdx.x;
  if (i >= R * C) return;
  int r = i / C, c = i % C;
  out[(size_t)c * R + r] = f2bf(in[i]);
}

// ---------------- transpose + split cast, all 3 weights (z = 0,1,2) ----------------
__global__ void tcast_split3_kernel(const float* __restrict__ Wq,
                                    const float* __restrict__ Wk,
                                    const float* __restrict__ Wv,
                                    unsigned short* __restrict__ oh,
                                    unsigned short* __restrict__ ol) {
  int i = blockIdx.x * blockDim.x + threadIdx.x;   // 0..524287
  int z = blockIdx.y;
  const float* in = (z == 0) ? Wq : (z == 1) ? Wk : Wv;
  int r = i >> 9, c = i & 511;                     // R=1024, C=512
  float v = in[i];
  unsigned short hb = f2bf(v);
  size_t o = (size_t)z * 524288 + (size_t)c * 1024 + r;
  oh[o] = hb;
  ol[o] = f2bf(v - bf2f(hb));
}

// ---------------- f gate: one wave per token row (pure f32) ----------------
__global__ __launch_bounds__(256) void fgate_kernel(const float* __restrict__ x,
                                                    const float* __restrict__ Wf,
                                                    const float* __restrict__ bfv,
                                                    float* __restrict__ fbuf) {
  int wid = (blockIdx.x * blockDim.x + threadIdx.x) >> 6;  // token row 0..4095
  int lane = threadIdx.x & 63;
  const float* xr = x + (size_t)wid * 1024;
  float acc[8] = {0.f, 0.f, 0.f, 0.f, 0.f, 0.f, 0.f, 0.f};
#pragma unroll 4
  for (int it = 0; it < 16; ++it) {
    int d = it * 64 + lane;
    float xv = xr[d];
    f32x4 w0 = *(const f32x4*)(Wf + (size_t)d * 8);
    f32x4 w1 = *(const f32x4*)(Wf + (size_t)d * 8 + 4);
    acc[0] += xv * w0[0]; acc[1] += xv * w0[1];
    acc[2] += xv * w0[2]; acc[3] += xv * w0[3];
    acc[4] += xv * w1[0]; acc[5] += xv * w1[1];
    acc[6] += xv * w1[2]; acc[7] += xv * w1[3];
  }
#pragma unroll
  for (int n = 0; n < 8; ++n) {
#pragma unroll
    for (int m = 1; m < 64; m <<= 1) acc[n] += __shfl_xor(acc[n], m, 64);
  }
  if (lane == 0) {
#pragma unroll
    for (int n = 0; n < 8; ++n)
      fbuf[(size_t)wid * 8 + n] = sigmoidf_fast(acc[n] + bfv[n]);
  }
}

// ---------------- causal depthwise conv (KC=4) + SiLU, all 3 tensors ----------------
__global__ void conv_silu_kernel(const float* __restrict__ pre,
                                 const float* __restrict__ cwq,
                                 const float* __restrict__ cwk,
                                 const float* __restrict__ cwv,
                                 float* __restrict__ outb) {
  int i = blockIdx.x * blockDim.x + threadIdx.x;  // B*L*512
  int which = blockIdx.y;
  const float* cw = (which == 0) ? cwq : (which == 1) ? cwk : cwv;
  const float* p = pre + (size_t)which * 2097152 + i;
  int c = i & 511;
  int l = (i >> 9) & 1023;
  float w0 = cw[c * 4 + 0], w1 = cw[c * 4 + 1], w2 = cw[c * 4 + 2], w3 = cw[c * 4 + 3];
  float acc = w3 * p[0];
  if (l >= 1) acc += w2 * p[-512];
  if (l >= 2) acc += w1 * p[-1024];
  if (l >= 3) acc += w0 * p[-1536];
  outb[(size_t)which * 2097152 + i] = acc * sigmoidf_fast(acc);
}

// ---------------- q/k/v pre-activation GEMM, one dispatch ----------------
// z = 0: q, plain 1-term bf16.  z = 1,2: k/v, split-bf16 3-term.
__global__ __launch_bounds__(256) void gemm_qkv_kernel(
    const unsigned short* __restrict__ Ah, const unsigned short* __restrict__ Al,
    const unsigned short* __restrict__ Bth, const unsigned short* __restrict__ Btl,
    float* __restrict__ C) {
  __shared__ unsigned short AshH[128][40];
  __shared__ unsigned short AshL[128][40];
  __shared__ unsigned short BshH[128][40];
  __shared__ unsigned short BshL[128][40];
  const int tid = threadIdx.x;
  const int wave = tid >> 6, lane = tid & 63;
  const int g = lane >> 4, lr = lane & 15;
  const int m0 = blockIdx.x * 128, n0 = blockIdx.y * 128;
  const int z = blockIdx.z;
  const bool split = (z != 0);
  const int Kd = 1024;
  const unsigned short* Bzh = Bth + (size_t)z * 524288;
  const unsigned short* Bzl = Btl + (size_t)z * 524288;
  float* Cz = C + (size_t)z * 2097152;
  const int wm = (wave >> 1) * 64, wn = (wave & 1) * 64;

  f32x4 acc[4][4];
#pragma unroll
  for (int a = 0; a < 4; ++a)
#pragma unroll
    for (int bq = 0; bq < 4; ++bq) acc[a][bq] = (f32x4){0.f, 0.f, 0.f, 0.f};

  for (int k0 = 0; k0 < Kd; k0 += 32) {
#pragma unroll
    for (int it = 0; it < 2; ++it) {
      int cch = tid + 256 * it;
      int r = cch >> 2, cc = cch & 3;
      size_t ao = (size_t)(m0 + r) * Kd + k0 + cc * 8;
      size_t bo = (size_t)(n0 + r) * Kd + k0 + cc * 8;
      *(i32x4*)&AshH[r][cc * 8] = *(const i32x4*)(Ah + ao);
      *(i32x4*)&BshH[r][cc * 8] = *(const i32x4*)(Bzh + bo);
      if (split) {
        *(i32x4*)&AshL[r][cc * 8] = *(const i32x4*)(Al + ao);
        *(i32x4*)&BshL[r][cc * 8] = *(const i32x4*)(Bzl + bo);
      }
    }
    __syncthreads();
    short8 afh[4], bfh[4];
#pragma unroll
    for (int mt = 0; mt < 4; ++mt) afh[mt] = *(const short8*)&AshH[wm + mt * 16 + lr][g * 8];
#pragma unroll
    for (int nt = 0; nt < 4; ++nt) bfh[nt] = *(const short8*)&BshH[wn + nt * 16 + lr][g * 8];
    if (split) {
      short8 afl[4], bfl[4];
#pragma unroll
      for (int mt = 0; mt < 4; ++mt) afl[mt] = *(const short8*)&AshL[wm + mt * 16 + lr][g * 8];
#pragma unroll
      for (int nt = 0; nt < 4; ++nt) bfl[nt] = *(const short8*)&BshL[wn + nt * 16 + lr][g * 8];
#pragma unroll
      for (int mt = 0; mt < 4; ++mt)
#pragma unroll
        for (int nt = 0; nt < 4; ++nt) {
          f32x4 a = acc[mt][nt];
          a = __builtin_amdgcn_mfma_f32_16x16x32_bf16(afl[mt], bfh[nt], a, 0, 0, 0);
          a = __builtin_amdgcn_mfma_f32_16x16x32_bf16(afh[mt], bfl[nt], a, 0, 0, 0);
          a = __builtin_amdgcn_mfma_f32_16x16x32_bf16(afh[mt], bfh[nt], a, 0, 0, 0);
          acc[mt][nt] = a;
        }
    } else {
#pragma unroll
      for (int mt = 0; mt < 4; ++mt)
#pragma unroll
        for (int nt = 0; nt < 4; ++nt)
          acc[mt][nt] = __builtin_amdgcn_mfma_f32_16x16x32_bf16(afh[mt], bfh[nt], acc[mt][nt], 0, 0, 0);
    }
    __syncthreads();
  }
#pragma unroll
  for (int mt = 0; mt < 4; ++mt)
#pragma unroll
    for (int nt = 0; nt < 4; ++nt)
#pragma unroll
      for (int r = 0; r < 4; ++r) {
        int m = m0 + wm + mt * 16 + g * 4 + r;
        int n = n0 + wn + nt * 16 + lr;
        Cz[(size_t)m * 512 + n] = acc[mt][nt][r];
      }
}

// ---------------- Wo projection GEMM with fused 4-partial y sum ----------------
// A[m][k] = bf16( sum_s ypart[s][m][k] )  (f32 accum, RNE -- identical to the
// old ysum_kernel), staged to LDS; B = Wo^T. C (4096,1024) f32.
__global__ __launch_bounds__(256) void gemm_wo_kernel(
    const unsigned short* __restrict__ yp, const unsigned short* __restrict__ Bt,
    float* __restrict__ C) {
  __shared__ unsigned short Ash[128][40];
  __shared__ unsigned short Bsh[128][40];
  const int tid = threadIdx.x;
  const int wave = tid >> 6, lane = tid & 63;
  const int g = lane >> 4, lr = lane & 15;
  const int m0 = blockIdx.x * 128, n0 = blockIdx.y * 128;
  const int Kd = 512, Nd = 1024;
  const int wm = (wave >> 1) * 64, wn = (wave & 1) * 64;

  f32x4 acc[4][4];
#pragma unroll
  for (int a = 0; a < 4; ++a)
#pragma unroll
    for (int bq = 0; bq < 4; ++bq) acc[a][bq] = (f32x4){0.f, 0.f, 0.f, 0.f};

  for (int k0 = 0; k0 < Kd; k0 += 32) {
#pragma unroll
    for (int it = 0; it < 2; ++it) {
      int cch = tid + 256 * it;
      int r = cch >> 2, cc = cch & 3;
      size_t ao = (size_t)(m0 + r) * Kd + k0 + cc * 8;
      u16x4 p0a = *(const u16x4*)(yp + ao);
      u16x4 p0b = *(const u16x4*)(yp + ao + 4);
      u16x4 p1a = *(const u16x4*)(yp + 2097152 + ao);
      u16x4 p1b = *(const u16x4*)(yp + 2097152 + ao + 4);
      u16x4 p2a = *(const u16x4*)(yp + 2 * 2097152 + ao);
      u16x4 p2b = *(const u16x4*)(yp + 2 * 2097152 + ao + 4);
      u16x4 p3a = *(const u16x4*)(yp + 3 * 2097152 + ao);
      u16x4 p3b = *(const u16x4*)(yp + 3 * 2097152 + ao + 4);
      u16x4 sa, sb2;
#pragma unroll
      for (int j = 0; j < 4; ++j) {
        sa[j]  = f2bf(bf2f(p0a[j]) + bf2f(p1a[j]) + bf2f(p2a[j]) + bf2f(p3a[j]));
        sb2[j] = f2bf(bf2f(p0b[j]) + bf2f(p1b[j]) + bf2f(p2b[j]) + bf2f(p3b[j]));
      }
      *(u16x4*)&Ash[r][cc * 8] = sa;
      *(u16x4*)&Ash[r][cc * 8 + 4] = sb2;
      *(i32x4*)&Bsh[r][cc * 8] = *(const i32x4*)(Bt + (size_t)(n0 + r) * Kd + k0 + cc * 8);
    }
    __syncthreads();
    short8 af[4], bfr[4];
#pragma unroll
    for (int mt = 0; mt < 4; ++mt) af[mt] = *(const short8*)&Ash[wm + mt * 16 + lr][g * 8];
#pragma unroll
    for (int nt = 0; nt < 4; ++nt) bfr[nt] = *(const short8*)&Bsh[wn + nt * 16 + lr][g * 8];
#pragma unroll
    for (int mt = 0; mt < 4; ++mt)
#pragma unroll
      for (int nt = 0; nt < 4; ++nt)
        acc[mt][nt] = __builtin_amdgcn_mfma_f32_16x16x32_bf16(af[mt], bfr[nt], acc[mt][nt], 0, 0, 0);
    __syncthreads();
  }
#pragma unroll
  for (int mt = 0; mt < 4; ++mt)
#pragma unroll
    for (int nt = 0; nt < 4; ++nt)
#pragma unroll
      for (int r = 0; r < 4; ++r) {
        int m = m0 + wm + mt * 16 + g * 4 + r;
        int n = n0 + wn + nt * 16 + lr;
        C[(size_t)m * Nd + n] = acc[mt][nt][r];
      }
}

// ---------------- recurrent scan: k-slice split (r11-verified, verbatim) ----------------
// Each k-row of H evolves independently. Split each (b,n) chain into 4 k-slices
// of 16 rows -> 128 blocks x 256 thr (4 waves), 1 wave/SIMD. Per wave: one 16x16
// C-tile (rows w in [16*wave,+16), cols k=lr), 6 MFMAs, 4 H f32/lane.
// y needs sum over k: each slice writes bf16 y-partials; Wo GEMM folds 4.
// Slice H planes (ping-pong): row k(local)=lr at byte lr*128, elem v at byte
// (2v) ^ ((lr&7)<<4)   [verified swizzle].
__global__ __launch_bounds__(256) void scan_kernel(
    const float* __restrict__ qbuf, const float* __restrict__ kbuf,
    const float* __restrict__ vbuf, const float* __restrict__ fbuf,
    const float* __restrict__ W, unsigned short* __restrict__ ypart,
    float* __restrict__ Hout) {
  const int tid = threadIdx.x;
  const int wave = tid >> 6, lane = tid & 63;
  const int g = lane >> 4, lr = lane & 15;
  const int bz = blockIdx.x;
  const int chain = bz >> 2, ks = bz & 3;
  const int b = chain >> 3, n = chain & 7;
  const int swz = (lr & 7) << 4;

  __shared__ unsigned short Hh[2][1024];   // 16x64 bf16 hi, ping-pong (2 KB each)
  __shared__ unsigned short Hl[2][1024];   // lo planes
  __shared__ float stage[2][16][192];      // 24 KB
  __shared__ float fs[2][16];
  __shared__ float yst[16][64];            // 4 KB y chunk buffer (f32)

  // zero plane 0 (H_0 = 0): 512 u32 per plane
  for (int i = tid; i < 512; i += 256) {
    ((unsigned*)Hh[0])[i] = 0u;
    ((unsigned*)Hl[0])[i] = 0u;
  }

  // W^T split hi/lo fragments: A[m=lr][k-chunk], m = w = 16*wave + lr
  const float* Wn = W + (size_t)n * 4096;
  short8 Af[2], Alw[2];
#pragma unroll
  for (int s = 0; s < 2; ++s) {
    int wcol = wave * 16 + lr;
    short8 ah, al;
#pragma unroll
    for (int j = 0; j < 8; ++j) {
      float wv = Wn[(size_t)(s * 32 + g * 8 + j) * 64 + wcol];
      unsigned short hb = f2bf(wv);
      ah[j] = (short)hb;
      al[j] = (short)f2bf(wv - bf2f(hb));
    }
    Af[s] = ah; Alw[s] = al;
  }

  // chunk staging: 16 steps x 192 floats = 768 f32x4 by 256 threads (3 each)
  auto stage_chunk = [&](int c, int buf) {
#pragma unroll
    for (int i = 0; i < 3; ++i) {
      int fi = tid + i * 256;
      int st = fi / 48, un = fi - st * 48;
      const float* basep = (un < 16) ? qbuf : (un < 32) ? kbuf : vbuf;
      f32x4 val = *(const f32x4*)(basep + (size_t)(b * 1024 + c * 16 + st) * 512 +
                                  n * 64 + (un & 15) * 4);
      *(f32x4*)&stage[buf][st][un * 4] = val;
    }
    if (tid < 16) fs[buf][tid] = fbuf[(size_t)(b * 1024 + c * 16 + tid) * 8 + n];
  };

  f32x4 HA = (f32x4){0.f, 0.f, 0.f, 0.f};  // H[ks*16+lr][w=16*wave+4g+r], f32 master
  int sb = 0, pp = 0;

  stage_chunk(0, 0);
  __syncthreads();

  const f32x4 zf = (f32x4){0.f, 0.f, 0.f, 0.f};
  const int bo0 = (16 * g) ^ swz;               // B-frag chunk 0 (v = g*8..)
  const int bo1 = (64 + 16 * g) ^ swz;          // chunk 1 (v = 32 + g*8..)
  const int wo = (32 * wave + 8 * g) ^ swz;     // H-write: 4 w at 16*wave+4g
  const float K2L2E = 2.885390081777927f;       // 2*log2(e)
  const int kg = ks * 16 + lr;                  // global k row of this lane

  for (int c = 0; c < 64; ++c) {
    if (c < 63) stage_chunk(c + 1, sb ^ 1);
    for (int tl = 0; tl < 16; ++tl) {
      const float* srow = &stage[sb][tl][0];

      // B-frags of H_t slice from plane pp (row lr, hi+lo, both v-chunks)
      const char* hrh = (const char*)(Hh[pp] + lr * 64);
      const char* hrl = (const char*)(Hl[pp] + lr * 64);
      short8 Bh0 = *(const short8*)(hrh + bo0);
      short8 Bh1 = *(const short8*)(hrh + bo1);
      short8 Bl0 = *(const short8*)(hrl + bo0);
      short8 Bl1 = *(const short8*)(hrl + bo1);

      // 6 MFMAs: 3-term split, 2 independent chains of 3
      f32x4 cX = __builtin_amdgcn_mfma_f32_16x16x32_bf16(Alw[0], Bh0, zf, 0, 0, 0);
      f32x4 cY = __builtin_amdgcn_mfma_f32_16x16x32_bf16(Alw[1], Bh1, zf, 0, 0, 0);
      cX = __builtin_amdgcn_mfma_f32_16x16x32_bf16(Af[0], Bl0, cX, 0, 0, 0);
      cY = __builtin_amdgcn_mfma_f32_16x16x32_bf16(Af[1], Bl1, cY, 0, 0, 0);
      cX = __builtin_amdgcn_mfma_f32_16x16x32_bf16(Af[0], Bh0, cX, 0, 0, 0);
      cY = __builtin_amdgcn_mfma_f32_16x16x32_bf16(Af[1], Bh1, cY, 0, 0, 0);

      float kval = srow[64 + kg];
      f32x4 vv = *(const f32x4*)(srow + 128 + wave * 16 + 4 * g);
      float fc = fs[sb][tl];
      f32x4 a0 = cX + cY;

      // tanh (exp2-fused, overflow-safe) + gate blend -> H_{t+1} (f32, exact)
#pragma unroll
      for (int r = 0; r < 4; ++r) {
        float arg = fmaf(kval, vv[r], a0[r]);
        float cd = fmaf(-2.f, __builtin_amdgcn_rcpf(1.f + __builtin_amdgcn_exp2f(arg * K2L2E)), 1.f);
        HA[r] = fmaf(fc, HA[r] - cd, cd);
      }

      // y slice-partials: sum over the 16 k-rows (= 16 lr lanes) via DPP.
      // Each wave owns disjoint w -> no cross-wave reduction needed.
      {
        float qs = srow[kg];
        float y0 = row_sum16(qs * HA[0]);
        float y1 = row_sum16(qs * HA[1]);
        float y2 = row_sum16(qs * HA[2]);
        float y3 = row_sum16(qs * HA[3]);
        if (lr == 15)
          *(f32x4*)&yst[tl][wave * 16 + 4 * g] = (f32x4){y0, y1, y2, y3};
      }

      // pack (cvt_pk) and write H_{t+1} to plane pp^1
      {
        char* hwh = (char*)(Hh[pp ^ 1] + lr * 64);
        char* hwl = (char*)(Hl[pp ^ 1] + lr * 64);
        unsigned ph0 = cvt_pk_bf16(HA[0], HA[1]);
        unsigned ph1 = cvt_pk_bf16(HA[2], HA[3]);
        float r0 = HA[0] - __builtin_bit_cast(float, ph0 << 16);
        float r1 = HA[1] - __builtin_bit_cast(float, ph0 & 0xFFFF0000u);
        float r2 = HA[2] - __builtin_bit_cast(float, ph1 << 16);
        float r3 = HA[3] - __builtin_bit_cast(float, ph1 & 0xFFFF0000u);
        *(u32x2*)(hwh + wo) = (u32x2){ph0, ph1};
        *(u32x2*)(hwl + wo) = (u32x2){cvt_pk_bf16(r0, r1), cvt_pk_bf16(r2, r3)};
      }

      __syncthreads();   // single barrier: plane pp^1 + (for chunk end) yst visible
      pp ^= 1;
    }

    // flush y slice-partials for this chunk (bf16), coalesced
    for (int i = tid; i < 1024; i += 256) {
      int tl2 = i >> 6, w = i & 63;
      ypart[(size_t)ks * 2097152 +
            (size_t)(b * 1024 + c * 16 + tl2) * 512 + n * 64 + w] = f2bf(yst[tl2][w]);
    }
    __syncthreads();   // protect yst reuse by next chunk
    sb ^= 1;
  }

  // H_final (f32 master): this slice owns rows ks*16..ks*16+16
  float* Ho = Hout + (size_t)(b * 8 + n) * 4096;
  *(f32x4*)&Ho[(size_t)kg * 64 + wave * 16 + g * 4] = HA;
}

// ---------------- launch ----------------
extern "C" void kernel_launch(void* const* d_in, const int* in_sizes, int n_in,
                              void* d_out, int out_size, void* d_ws, size_t ws_size,
                              hipStream_t stream) {
  const float* x   = (const float*)d_in[0];
  const float* Wq  = (const float*)d_in[1];
  const float* Wk  = (const float*)d_in[2];
  const float* Wv  = (const float*)d_in[3];
  const float* Wf  = (const float*)d_in[4];
  const float* bfv = (const float*)d_in[5];
  const float* cwq = (const float*)d_in[6];
  const float* cwk = (const float*)d_in[7];
  const float* cwv = (const float*)d_in[8];
  const float* W   = (const float*)d_in[9];
  const float* Wo  = (const float*)d_in[10];
  float* outp = (float*)d_out;

  char* ws = (char*)d_ws;
  size_t off = 0;
  auto alloc = [&](size_t bytes) {
    char* pp = ws + off;
    off = (off + bytes + 255) & ~(size_t)255;
    return pp;
  };
  unsigned short* xbh  = (unsigned short*)alloc((size_t)4194304 * 2);
  unsigned short* xbl  = (unsigned short*)alloc((size_t)4194304 * 2);
  unsigned short* wtbh = (unsigned short*)alloc((size_t)3 * 524288 * 2);
  unsigned short* wtbl = (unsigned short*)alloc((size_t)3 * 524288 * 2);
  float* pre  = (float*)alloc((size_t)3 * 2097152 * 4);   // aliased: y partials
  float* qkv  = (float*)alloc((size_t)3 * 2097152 * 4);
  float* fbuf = (float*)alloc((size_t)32768 * 4);
  unsigned short* wot = (unsigned short*)alloc((size_t)524288 * 2);
  unsigned short* ypart = (unsigned short*)pre;  // pre is dead after conv_silu

  // casts / transposes (split hi/lo for the amplified paths)
  cast_split_kernel<<<4096, 256, 0, stream>>>(x, xbh, xbl, 1048576);
  dim3 gt(2048, 3, 1);
  tcast_split3_kernel<<<gt, 256, 0, stream>>>(Wq, Wk, Wv, wtbh, wtbl);
  // gate
  fgate_kernel<<<1024, 256, 0, stream>>>(x, Wf, bfv, fbuf);
  // q/k/v pre-activations in ONE dispatch (z=0 plain, z=1,2 split)
  dim3 g1(32, 4, 3);
  gemm_qkv_kernel<<<g1, 256, 0, stream>>>(xbh, xbl, wtbh, wtbl, pre);
  // conv + silu (all three in one launch); pre is dead afterwards
  dim3 gc(8192, 3, 1);
  conv_silu_kernel<<<gc, 256, 0, stream>>>(pre, cwq, cwk, cwv, qkv);
  // recurrent scan: 128 blocks (32 chains x 4 k-slices) x 256 threads
  scan_kernel<<<128, 256, 0, stream>>>(qkv, qkv + 2097152, qkv + 2 * 2097152, fbuf, W,
                                       ypart, outp + 4194304);
  // output projection with fused 4-partial y sum
  tcast_kernel<<<2048, 256, 0, stream>>>(Wo, wot, 512, 1024);
  dim3 g2(32, 8, 1);
  gemm_wo_kernel<<<g2, 256, 0, stream>>>(ypart, wot, outp);
}

// Round 16
// 686.211 us; speedup vs baseline: 2.2034x; 1.0265x over previous
//
#include <hip/hip_runtime.h>
#include <hip/hip_bf16.h>

typedef __attribute__((ext_vector_type(4))) float f32x4;
typedef __attribute__((ext_vector_type(8))) short short8;
typedef __attribute__((ext_vector_type(4))) int i32x4;
typedef __attribute__((ext_vector_type(2))) unsigned int u32x2;
typedef __attribute__((ext_vector_type(4))) unsigned short u16x4;

static __device__ __forceinline__ unsigned short f2bf(float f) {
  unsigned u = __builtin_bit_cast(unsigned, f);
  u = u + 0x7FFFu + ((u >> 16) & 1u);   // RNE
  return (unsigned short)(u >> 16);
}
static __device__ __forceinline__ float bf2f(unsigned short b) {
  unsigned u = ((unsigned)b) << 16;
  return __builtin_bit_cast(float, u);
}
static __device__ __forceinline__ float sigmoidf_fast(float x) {
  return __builtin_amdgcn_rcpf(1.f + __expf(-x));
}
// packed bf16 pair: low16 = bf16(a), high16 = bf16(b)
static __device__ __forceinline__ unsigned cvt_pk_bf16(float a, float b) {
  unsigned d;
  asm volatile("v_cvt_pk_bf16_f32 %0, %1, %2" : "=v"(d) : "v"(a), "v"(b));
  return d;
}
// Row-wise (16-lane DPP row) inclusive sum; total lands in lane (lane&15)==15.
static __device__ __forceinline__ float row_sum16(float v) {
  int x;
  x = __builtin_amdgcn_update_dpp(0, __builtin_bit_cast(int, v), 0x111, 0xF, 0xF, true);
  v += __builtin_bit_cast(float, x);   // row_shr:1
  x = __builtin_amdgcn_update_dpp(0, __builtin_bit_cast(int, v), 0x112, 0xF, 0xF, true);
  v += __builtin_bit_cast(float, x);   // row_shr:2
  x = __builtin_amdgcn_update_dpp(0, __builtin_bit_cast(int, v), 0x114, 0xF, 0xF, true);
  v += __builtin_bit_cast(float, x);   // row_shr:4
  x = __builtin_amdgcn_update_dpp(0, __builtin_bit_cast(int, v), 0x118, 0xF, 0xF, true);
  v += __builtin_bit_cast(float, x);   // row_shr:8
  return v;
}

// ---------------- prep: cast x -> hi/lo bf16 pair AND f gate (fused) ----------------
// 1024 blocks x 256 thr. Block handles 4 rows of x: cast (4 f32x4/thread) + gate
// (one wave per row, same math as the old fgate_kernel).
__global__ __launch_bounds__(256) void prep_kernel(const float* __restrict__ x,
                                                   const float* __restrict__ Wf,
                                                   const float* __restrict__ bfv,
                                                   unsigned short* __restrict__ oh,
                                                   unsigned short* __restrict__ ol,
                                                   float* __restrict__ fbuf) {
  const int tid = threadIdx.x;
  // cast part: 1024 f32x4 per block
  int base = blockIdx.x * 1024;
#pragma unroll
  for (int i = 0; i < 4; ++i) {
    int idx = base + tid + i * 256;
    f32x4 v = ((const f32x4*)x)[idx];
    u16x4 h, l;
#pragma unroll
    for (int j = 0; j < 4; ++j) {
      unsigned short hb = f2bf(v[j]);
      h[j] = hb;
      l[j] = f2bf(v[j] - bf2f(hb));
    }
    ((u16x4*)oh)[idx] = h;
    ((u16x4*)ol)[idx] = l;
  }
  // gate part: wave per row (4 rows/block)
  int wid = blockIdx.x * 4 + (tid >> 6);
  int lane = tid & 63;
  const float* xr = x + (size_t)wid * 1024;
  float acc[8] = {0.f, 0.f, 0.f, 0.f, 0.f, 0.f, 0.f, 0.f};
#pragma unroll 4
  for (int it = 0; it < 16; ++it) {
    int d = it * 64 + lane;
    float xv = xr[d];
    f32x4 w0 = *(const f32x4*)(Wf + (size_t)d * 8);
    f32x4 w1 = *(const f32x4*)(Wf + (size_t)d * 8 + 4);
    acc[0] += xv * w0[0]; acc[1] += xv * w0[1];
    acc[2] += xv * w0[2]; acc[3] += xv * w0[3];
    acc[4] += xv * w1[0]; acc[5] += xv * w1[1];
    acc[6] += xv * w1[2]; acc[7] += xv * w1[3];
  }
#pragma unroll
  for (int n = 0; n < 8; ++n) {
#pragma unroll
    for (int m = 1; m < 64; m <<= 1) acc[n] += __shfl_xor(acc[n], m, 64);
  }
  if (lane == 0) {
#pragma unroll
    for (int n = 0; n < 8; ++n)
      fbuf[(size_t)wid * 8 + n] = sigmoidf_fast(acc[n] + bfv[n]);
  }
}

// ---------------- transpose + cast: (R,C) f32 -> (C,R) bf16 ----------------
__global__ void tcast_kernel(const float* __restrict__ in,
                             unsigned short* __restrict__ out, int R, int C) {
  int i = blockIdx.x * blockDim.x + threadIdx.x;
  if (i >= R * C) return;
  int r = i / C, c = i % C;
  out[(size_t)c * R + r] = f2bf(in[i]);
}

// ---------------- transpose + split cast, all 3 weights (z = 0,1,2) ----------------
__global__ void tcast_split3_kernel(const float* __restrict__ Wq,
                                    const float* __restrict__ Wk,
                                    const float* __restrict__ Wv,
                                    unsigned short* __restrict__ oh,
                                    unsigned short* __restrict__ ol) {
  int i = blockIdx.x * blockDim.x + threadIdx.x;   // 0..524287
  int z = blockIdx.y;
  const float* in = (z == 0) ? Wq : (z == 1) ? Wk : Wv;
  int r = i >> 9, c = i & 511;                     // R=1024, C=512
  float v = in[i];
  unsigned short hb = f2bf(v);
  size_t o = (size_t)z * 524288 + (size_t)c * 1024 + r;
  oh[o] = hb;
  ol[o] = f2bf(v - bf2f(hb));
}

// ---------------- causal depthwise conv (KC=4) + SiLU, all 3 tensors ----------------
__global__ void conv_silu_kernel(const float* __restrict__ pre,
                                 const float* __restrict__ cwq,
                                 const float* __restrict__ cwk,
                                 const float* __restrict__ cwv,
                                 float* __restrict__ outb) {
  int i = blockIdx.x * blockDim.x + threadIdx.x;  // B*L*512
  int which = blockIdx.y;
  const float* cw = (which == 0) ? cwq : (which == 1) ? cwk : cwv;
  const float* p = pre + (size_t)which * 2097152 + i;
  int c = i & 511;
  int l = (i >> 9) & 1023;
  float w0 = cw[c * 4 + 0], w1 = cw[c * 4 + 1], w2 = cw[c * 4 + 2], w3 = cw[c * 4 + 3];
  float acc = w3 * p[0];
  if (l >= 1) acc += w2 * p[-512];
  if (l >= 2) acc += w1 * p[-1024];
  if (l >= 3) acc += w0 * p[-1536];
  outb[(size_t)which * 2097152 + i] = acc * sigmoidf_fast(acc);
}

// ---------------- q/k/v pre-activation GEMM, one dispatch ----------------
// z = 0: q, plain 1-term bf16.  z = 1,2: k/v, split-bf16 3-term.
__global__ __launch_bounds__(256) void gemm_qkv_kernel(
    const unsigned short* __restrict__ Ah, const unsigned short* __restrict__ Al,
    const unsigned short* __restrict__ Bth, const unsigned short* __restrict__ Btl,
    float* __restrict__ C) {
  __shared__ unsigned short AshH[128][40];
  __shared__ unsigned short AshL[128][40];
  __shared__ unsigned short BshH[128][40];
  __shared__ unsigned short BshL[128][40];
  const int tid = threadIdx.x;
  const int wave = tid >> 6, lane = tid & 63;
  const int g = lane >> 4, lr = lane & 15;
  const int m0 = blockIdx.x * 128, n0 = blockIdx.y * 128;
  const int z = blockIdx.z;
  const bool split = (z != 0);
  const int Kd = 1024;
  const unsigned short* Bzh = Bth + (size_t)z * 524288;
  const unsigned short* Bzl = Btl + (size_t)z * 524288;
  float* Cz = C + (size_t)z * 2097152;
  const int wm = (wave >> 1) * 64, wn = (wave & 1) * 64;

  f32x4 acc[4][4];
#pragma unroll
  for (int a = 0; a < 4; ++a)
#pragma unroll
    for (int bq = 0; bq < 4; ++bq) acc[a][bq] = (f32x4){0.f, 0.f, 0.f, 0.f};

  for (int k0 = 0; k0 < Kd; k0 += 32) {
#pragma unroll
    for (int it = 0; it < 2; ++it) {
      int cch = tid + 256 * it;
      int r = cch >> 2, cc = cch & 3;
      size_t ao = (size_t)(m0 + r) * Kd + k0 + cc * 8;
      size_t bo = (size_t)(n0 + r) * Kd + k0 + cc * 8;
      *(i32x4*)&AshH[r][cc * 8] = *(const i32x4*)(Ah + ao);
      *(i32x4*)&BshH[r][cc * 8] = *(const i32x4*)(Bzh + bo);
      if (split) {
        *(i32x4*)&AshL[r][cc * 8] = *(const i32x4*)(Al + ao);
        *(i32x4*)&BshL[r][cc * 8] = *(const i32x4*)(Bzl + bo);
      }
    }
    __syncthreads();
    short8 afh[4], bfh[4];
#pragma unroll
    for (int mt = 0; mt < 4; ++mt) afh[mt] = *(const short8*)&AshH[wm + mt * 16 + lr][g * 8];
#pragma unroll
    for (int nt = 0; nt < 4; ++nt) bfh[nt] = *(const short8*)&BshH[wn + nt * 16 + lr][g * 8];
    if (split) {
      short8 afl[4], bfl[4];
#pragma unroll
      for (int mt = 0; mt < 4; ++mt) afl[mt] = *(const short8*)&AshL[wm + mt * 16 + lr][g * 8];
#pragma unroll
      for (int nt = 0; nt < 4; ++nt) bfl[nt] = *(const short8*)&BshL[wn + nt * 16 + lr][g * 8];
#pragma unroll
      for (int mt = 0; mt < 4; ++mt)
#pragma unroll
        for (int nt = 0; nt < 4; ++nt) {
          f32x4 a = acc[mt][nt];
          a = __builtin_amdgcn_mfma_f32_16x16x32_bf16(afl[mt], bfh[nt], a, 0, 0, 0);
          a = __builtin_amdgcn_mfma_f32_16x16x32_bf16(afh[mt], bfl[nt], a, 0, 0, 0);
          a = __builtin_amdgcn_mfma_f32_16x16x32_bf16(afh[mt], bfh[nt], a, 0, 0, 0);
          acc[mt][nt] = a;
        }
    } else {
#pragma unroll
      for (int mt = 0; mt < 4; ++mt)
#pragma unroll
        for (int nt = 0; nt < 4; ++nt)
          acc[mt][nt] = __builtin_amdgcn_mfma_f32_16x16x32_bf16(afh[mt], bfh[nt], acc[mt][nt], 0, 0, 0);
    }
    __syncthreads();
  }
#pragma unroll
  for (int mt = 0; mt < 4; ++mt)
#pragma unroll
    for (int nt = 0; nt < 4; ++nt)
#pragma unroll
      for (int r = 0; r < 4; ++r) {
        int m = m0 + wm + mt * 16 + g * 4 + r;
        int n = n0 + wn + nt * 16 + lr;
        Cz[(size_t)m * 512 + n] = acc[mt][nt][r];
      }
}

// ---------------- Wo projection GEMM with fused 4-partial y sum ----------------
__global__ __launch_bounds__(256) void gemm_wo_kernel(
    const unsigned short* __restrict__ yp, const unsigned short* __restrict__ Bt,
    float* __restrict__ C) {
  __shared__ unsigned short Ash[128][40];
  __shared__ unsigned short Bsh[128][40];
  const int tid = threadIdx.x;
  const int wave = tid >> 6, lane = tid & 63;
  const int g = lane >> 4, lr = lane & 15;
  const int m0 = blockIdx.x * 128, n0 = blockIdx.y * 128;
  const int Kd = 512, Nd = 1024;
  const int wm = (wave >> 1) * 64, wn = (wave & 1) * 64;

  f32x4 acc[4][4];
#pragma unroll
  for (int a = 0; a < 4; ++a)
#pragma unroll
    for (int bq = 0; bq < 4; ++bq) acc[a][bq] = (f32x4){0.f, 0.f, 0.f, 0.f};

  for (int k0 = 0; k0 < Kd; k0 += 32) {
#pragma unroll
    for (int it = 0; it < 2; ++it) {
      int cch = tid + 256 * it;
      int r = cch >> 2, cc = cch & 3;
      size_t ao = (size_t)(m0 + r) * Kd + k0 + cc * 8;
      u16x4 p0a = *(const u16x4*)(yp + ao);
      u16x4 p0b = *(const u16x4*)(yp + ao + 4);
      u16x4 p1a = *(const u16x4*)(yp + 2097152 + ao);
      u16x4 p1b = *(const u16x4*)(yp + 2097152 + ao + 4);
      u16x4 p2a = *(const u16x4*)(yp + 2 * 2097152 + ao);
      u16x4 p2b = *(const u16x4*)(yp + 2 * 2097152 + ao + 4);
      u16x4 p3a = *(const u16x4*)(yp + 3 * 2097152 + ao);
      u16x4 p3b = *(const u16x4*)(yp + 3 * 2097152 + ao + 4);
      u16x4 sa, sb2;
#pragma unroll
      for (int j = 0; j < 4; ++j) {
        sa[j]  = f2bf(bf2f(p0a[j]) + bf2f(p1a[j]) + bf2f(p2a[j]) + bf2f(p3a[j]));
        sb2[j] = f2bf(bf2f(p0b[j]) + bf2f(p1b[j]) + bf2f(p2b[j]) + bf2f(p3b[j]));
      }
      *(u16x4*)&Ash[r][cc * 8] = sa;
      *(u16x4*)&Ash[r][cc * 8 + 4] = sb2;
      *(i32x4*)&Bsh[r][cc * 8] = *(const i32x4*)(Bt + (size_t)(n0 + r) * Kd + k0 + cc * 8);
    }
    __syncthreads();
    short8 af[4], bfr[4];
#pragma unroll
    for (int mt = 0; mt < 4; ++mt) af[mt] = *(const short8*)&Ash[wm + mt * 16 + lr][g * 8];
#pragma unroll
    for (int nt = 0; nt < 4; ++nt) bfr[nt] = *(const short8*)&Bsh[wn + nt * 16 + lr][g * 8];
#pragma unroll
    for (int mt = 0; mt < 4; ++mt)
#pragma unroll
      for (int nt = 0; nt < 4; ++nt)
        acc[mt][nt] = __builtin_amdgcn_mfma_f32_16x16x32_bf16(af[mt], bfr[nt], acc[mt][nt], 0, 0, 0);
    __syncthreads();
  }
#pragma unroll
  for (int mt = 0; mt < 4; ++mt)
#pragma unroll
    for (int nt = 0; nt < 4; ++nt)
#pragma unroll
      for (int r = 0; r < 4; ++r) {
        int m = m0 + wm + mt * 16 + g * 4 + r;
        int n = n0 + wn + nt * 16 + lr;
        C[(size_t)m * Nd + n] = acc[mt][nt][r];
      }
}

// ---------------- recurrent scan: k-slice split (r11-verified) ----------------
// r16 delta: H pack+write issued BEFORE the y-DPP block, so the y VALU chain
// overlaps the ds_write retire and the barrier finds the writes complete.
// Slice H planes (ping-pong): row lr at byte lr*128, elem v at (2v)^((lr&7)<<4).
__global__ __launch_bounds__(256) void scan_kernel(
    const float* __restrict__ qbuf, const float* __restrict__ kbuf,
    const float* __restrict__ vbuf, const float* __restrict__ fbuf,
    const float* __restrict__ W, unsigned short* __restrict__ ypart,
    float* __restrict__ Hout) {
  const int tid = threadIdx.x;
  const int wave = tid >> 6, lane = tid & 63;
  const int g = lane >> 4, lr = lane & 15;
  const int bz = blockIdx.x;
  const int chain = bz >> 2, ks = bz & 3;
  const int b = chain >> 3, n = chain & 7;
  const int swz = (lr & 7) << 4;

  __shared__ unsigned short Hh[2][1024];   // 16x64 bf16 hi, ping-pong
  __shared__ unsigned short Hl[2][1024];   // lo planes
  __shared__ float stage[2][16][192];      // 24 KB
  __shared__ float fs[2][16];
  __shared__ float yst[16][64];            // 4 KB

  for (int i = tid; i < 512; i += 256) {
    ((unsigned*)Hh[0])[i] = 0u;
    ((unsigned*)Hl[0])[i] = 0u;
  }

  // W^T split hi/lo fragments: A[m=lr][k-chunk], m = w = 16*wave + lr
  const float* Wn = W + (size_t)n * 4096;
  short8 Af[2], Alw[2];
#pragma unroll
  for (int s = 0; s < 2; ++s) {
    int wcol = wave * 16 + lr;
    short8 ah, al;
#pragma unroll
    for (int j = 0; j < 8; ++j) {
      float wv = Wn[(size_t)(s * 32 + g * 8 + j) * 64 + wcol];
      unsigned short hb = f2bf(wv);
      ah[j] = (short)hb;
      al[j] = (short)f2bf(wv - bf2f(hb));
    }
    Af[s] = ah; Alw[s] = al;
  }

  // chunk staging: 16 steps x 192 floats = 768 f32x4 by 256 threads (3 each)
  auto stage_chunk = [&](int c, int buf) {
#pragma unroll
    for (int i = 0; i < 3; ++i) {
      int fi = tid + i * 256;
      int st = fi / 48, un = fi - st * 48;
      const float* basep = (un < 16) ? qbuf : (un < 32) ? kbuf : vbuf;
      f32x4 val = *(const f32x4*)(basep + (size_t)(b * 1024 + c * 16 + st) * 512 +
                                  n * 64 + (un & 15) * 4);
      *(f32x4*)&stage[buf][st][un * 4] = val;
    }
    if (tid < 16) fs[buf][tid] = fbuf[(size_t)(b * 1024 + c * 16 + tid) * 8 + n];
  };

  f32x4 HA = (f32x4){0.f, 0.f, 0.f, 0.f};  // H[ks*16+lr][w=16*wave+4g+r], f32 master
  int sb = 0, pp = 0;

  stage_chunk(0, 0);
  __syncthreads();

  const f32x4 zf = (f32x4){0.f, 0.f, 0.f, 0.f};
  const int bo0 = (16 * g) ^ swz;               // B-frag chunk 0
  const int bo1 = (64 + 16 * g) ^ swz;          // chunk 1
  const int wo = (32 * wave + 8 * g) ^ swz;     // H-write
  const float K2L2E = 2.885390081777927f;       // 2*log2(e)
  const int kg = ks * 16 + lr;                  // global k row of this lane

  for (int c = 0; c < 64; ++c) {
    if (c < 63) stage_chunk(c + 1, sb ^ 1);
    for (int tl = 0; tl < 16; ++tl) {
      const float* srow = &stage[sb][tl][0];

      // B-frags of H_t slice from plane pp
      const char* hrh = (const char*)(Hh[pp] + lr * 64);
      const char* hrl = (const char*)(Hl[pp] + lr * 64);
      short8 Bh0 = *(const short8*)(hrh + bo0);
      short8 Bh1 = *(const short8*)(hrh + bo1);
      short8 Bl0 = *(const short8*)(hrl + bo0);
      short8 Bl1 = *(const short8*)(hrl + bo1);

      // 6 MFMAs: 3-term split, 2 independent chains of 3
      f32x4 cX = __builtin_amdgcn_mfma_f32_16x16x32_bf16(Alw[0], Bh0, zf, 0, 0, 0);
      f32x4 cY = __builtin_amdgcn_mfma_f32_16x16x32_bf16(Alw[1], Bh1, zf, 0, 0, 0);
      cX = __builtin_amdgcn_mfma_f32_16x16x32_bf16(Af[0], Bl0, cX, 0, 0, 0);
      cY = __builtin_amdgcn_mfma_f32_16x16x32_bf16(Af[1], Bl1, cY, 0, 0, 0);
      cX = __builtin_amdgcn_mfma_f32_16x16x32_bf16(Af[0], Bh0, cX, 0, 0, 0);
      cY = __builtin_amdgcn_mfma_f32_16x16x32_bf16(Af[1], Bh1, cY, 0, 0, 0);

      float kval = srow[64 + kg];
      f32x4 vv = *(const f32x4*)(srow + 128 + wave * 16 + 4 * g);
      float fc = fs[sb][tl];
      f32x4 a0 = cX + cY;

      // tanh (exp2-fused, overflow-safe) + gate blend -> H_{t+1} (f32, exact)
#pragma unroll
      for (int r = 0; r < 4; ++r) {
        float arg = fmaf(kval, vv[r], a0[r]);
        float cd = fmaf(-2.f, __builtin_amdgcn_rcpf(1.f + __builtin_amdgcn_exp2f(arg * K2L2E)), 1.f);
        HA[r] = fmaf(fc, HA[r] - cd, cd);
      }

      // pack (cvt_pk) and write H_{t+1} to plane pp^1 FIRST (retires under y-VALU)
      {
        char* hwh = (char*)(Hh[pp ^ 1] + lr * 64);
        char* hwl = (char*)(Hl[pp ^ 1] + lr * 64);
        unsigned ph0 = cvt_pk_bf16(HA[0], HA[1]);
        unsigned ph1 = cvt_pk_bf16(HA[2], HA[3]);
        float r0 = HA[0] - __builtin_bit_cast(float, ph0 << 16);
        float r1 = HA[1] - __builtin_bit_cast(float, ph0 & 0xFFFF0000u);
        float r2 = HA[2] - __builtin_bit_cast(float, ph1 << 16);
        float r3 = HA[3] - __builtin_bit_cast(float, ph1 & 0xFFFF0000u);
        *(u32x2*)(hwh + wo) = (u32x2){ph0, ph1};
        *(u32x2*)(hwl + wo) = (u32x2){cvt_pk_bf16(r0, r1), cvt_pk_bf16(r2, r3)};
      }

      // y slice-partials: DPP row-sum over the 16 k-lanes (VALU covers the writes)
      {
        float qs = srow[kg];
        float y0 = row_sum16(qs * HA[0]);
        float y1 = row_sum16(qs * HA[1]);
        float y2 = row_sum16(qs * HA[2]);
        float y3 = row_sum16(qs * HA[3]);
        if (lr == 15)
          *(f32x4*)&yst[tl][wave * 16 + 4 * g] = (f32x4){y0, y1, y2, y3};
      }

      __syncthreads();   // single barrier: plane pp^1 + yst visible
      pp ^= 1;
    }

    // flush y slice-partials for this chunk (bf16), coalesced
    for (int i = tid; i < 1024; i += 256) {
      int tl2 = i >> 6, w = i & 63;
      ypart[(size_t)ks * 2097152 +
            (size_t)(b * 1024 + c * 16 + tl2) * 512 + n * 64 + w] = f2bf(yst[tl2][w]);
    }
    __syncthreads();   // protect yst reuse by next chunk
    sb ^= 1;
  }

  // H_final (f32 master): this slice owns rows ks*16..ks*16+16
  float* Ho = Hout + (size_t)(b * 8 + n) * 4096;
  *(f32x4*)&Ho[(size_t)kg * 64 + wave * 16 + g * 4] = HA;
}

// ---------------- launch ----------------
extern "C" void kernel_launch(void* const* d_in, const int* in_sizes, int n_in,
                              void* d_out, int out_size, void* d_ws, size_t ws_size,
                              hipStream_t stream) {
  const float* x   = (const float*)d_in[0];
  const float* Wq  = (const float*)d_in[1];
  const float* Wk  = (const float*)d_in[2];
  const float* Wv  = (const float*)d_in[3];
  const float* Wf  = (const float*)d_in[4];
  const float* bfv = (const float*)d_in[5];
  const float* cwq = (const float*)d_in[6];
  const float* cwk = (const float*)d_in[7];
  const float* cwv = (const float*)d_in[8];
  const float* W   = (const float*)d_in[9];
  const float* Wo  = (const float*)d_in[10];
  float* outp = (float*)d_out;

  char* ws = (char*)d_ws;
  size_t off = 0;
  auto alloc = [&](size_t bytes) {
    char* pp = ws + off;
    off = (off + bytes + 255) & ~(size_t)255;
    return pp;
  };
  unsigned short* xbh  = (unsigned short*)alloc((size_t)4194304 * 2);
  unsigned short* xbl  = (unsigned short*)alloc((size_t)4194304 * 2);
  unsigned short* wtbh = (unsigned short*)alloc((size_t)3 * 524288 * 2);
  unsigned short* wtbl = (unsigned short*)alloc((size_t)3 * 524288 * 2);
  float* pre  = (float*)alloc((size_t)3 * 2097152 * 4);   // aliased: y partials
  float* qkv  = (float*)alloc((size_t)3 * 2097152 * 4);
  float* fbuf = (float*)alloc((size_t)32768 * 4);
  unsigned short* wot = (unsigned short*)alloc((size_t)524288 * 2);
  unsigned short* ypart = (unsigned short*)pre;  // pre is dead after conv_silu

  // prep: cast x (hi/lo) + f gate, fused
  prep_kernel<<<1024, 256, 0, stream>>>(x, Wf, bfv, xbh, xbl, fbuf);
  // weight transposes (split hi/lo)
  dim3 gt(2048, 3, 1);
  tcast_split3_kernel<<<gt, 256, 0, stream>>>(Wq, Wk, Wv, wtbh, wtbl);
  // q/k/v pre-activations in ONE dispatch (z=0 plain, z=1,2 split)
  dim3 g1(32, 4, 3);
  gemm_qkv_kernel<<<g1, 256, 0, stream>>>(xbh, xbl, wtbh, wtbl, pre);
  // conv + silu (all three in one launch); pre is dead afterwards
  dim3 gc(8192, 3, 1);
  conv_silu_kernel<<<gc, 256, 0, stream>>>(pre, cwq, cwk, cwv, qkv);
  // recurrent scan: 128 blocks (32 chains x 4 k-slices) x 256 threads
  scan_kernel<<<128, 256, 0, stream>>>(qkv, qkv + 2097152, qkv + 2 * 2097152, fbuf, W,
                                       ypart, outp + 4194304);
  // output projection with fused 4-partial y sum
  tcast_kernel<<<2048, 256, 0, stream>>>(Wo, wot, 512, 1024);
  dim3 g2(32, 8, 1);
  gemm_wo_kernel<<<g2, 256, 0, stream>>>(ypart, wot, outp);
}

// Round 17
// 642.468 us; speedup vs baseline: 2.3535x; 1.0681x over previous
//
#include <hip/hip_runtime.h>
#include <hip/hip_bf16.h>

typedef __attribute__((ext_vector_type(4))) float f32x4;
typedef __attribute__((ext_vector_type(8))) short short8;
typedef __attribute__((ext_vector_type(4))) int i32x4;
typedef __attribute__((ext_vector_type(2))) unsigned int u32x2;
typedef __attribute__((ext_vector_type(4))) unsigned short u16x4;
typedef __attribute__((ext_vector_type(8))) unsigned short u16x8;

static __device__ __forceinline__ unsigned short f2bf(float f) {
  unsigned u = __builtin_bit_cast(unsigned, f);
  u = u + 0x7FFFu + ((u >> 16) & 1u);   // RNE
  return (unsigned short)(u >> 16);
}
static __device__ __forceinline__ float bf2f(unsigned short b) {
  unsigned u = ((unsigned)b) << 16;
  return __builtin_bit_cast(float, u);
}
static __device__ __forceinline__ float sigmoidf_fast(float x) {
  return __builtin_amdgcn_rcpf(1.f + __expf(-x));
}
// packed bf16 pair: low16 = bf16(a), high16 = bf16(b)
static __device__ __forceinline__ unsigned cvt_pk_bf16(float a, float b) {
  unsigned d;
  asm volatile("v_cvt_pk_bf16_f32 %0, %1, %2" : "=v"(d) : "v"(a), "v"(b));
  return d;
}
// Row-wise (16-lane DPP row) inclusive sum; total lands in lane (lane&15)==15.
static __device__ __forceinline__ float row_sum16(float v) {
  int x;
  x = __builtin_amdgcn_update_dpp(0, __builtin_bit_cast(int, v), 0x111, 0xF, 0xF, true);
  v += __builtin_bit_cast(float, x);   // row_shr:1
  x = __builtin_amdgcn_update_dpp(0, __builtin_bit_cast(int, v), 0x112, 0xF, 0xF, true);
  v += __builtin_bit_cast(float, x);   // row_shr:2
  x = __builtin_amdgcn_update_dpp(0, __builtin_bit_cast(int, v), 0x114, 0xF, 0xF, true);
  v += __builtin_bit_cast(float, x);   // row_shr:4
  x = __builtin_amdgcn_update_dpp(0, __builtin_bit_cast(int, v), 0x118, 0xF, 0xF, true);
  v += __builtin_bit_cast(float, x);   // row_shr:8
  return v;
}
// LDS-only barrier: drains this wave's LDS ops, syncs waves -- skips the vmcnt(0)
// drain __syncthreads would add (global loads/stores here never need step-sync).
static __device__ __forceinline__ void lds_barrier() {
  asm volatile("s_waitcnt lgkmcnt(0)" ::: "memory");
  __builtin_amdgcn_s_barrier();
}

// ---------------- prep: cast x -> hi/lo bf16 pair AND f gate (fused) ----------------
__global__ __launch_bounds__(256) void prep_kernel(const float* __restrict__ x,
                                                   const float* __restrict__ Wf,
                                                   const float* __restrict__ bfv,
                                                   unsigned short* __restrict__ oh,
                                                   unsigned short* __restrict__ ol,
                                                   float* __restrict__ fbuf) {
  const int tid = threadIdx.x;
  int base = blockIdx.x * 1024;
#pragma unroll
  for (int i = 0; i < 4; ++i) {
    int idx = base + tid + i * 256;
    f32x4 v = ((const f32x4*)x)[idx];
    u16x4 h, l;
#pragma unroll
    for (int j = 0; j < 4; ++j) {
      unsigned short hb = f2bf(v[j]);
      h[j] = hb;
      l[j] = f2bf(v[j] - bf2f(hb));
    }
    ((u16x4*)oh)[idx] = h;
    ((u16x4*)ol)[idx] = l;
  }
  int wid = blockIdx.x * 4 + (tid >> 6);
  int lane = tid & 63;
  const float* xr = x + (size_t)wid * 1024;
  float acc[8] = {0.f, 0.f, 0.f, 0.f, 0.f, 0.f, 0.f, 0.f};
#pragma unroll 4
  for (int it = 0; it < 16; ++it) {
    int d = it * 64 + lane;
    float xv = xr[d];
    f32x4 w0 = *(const f32x4*)(Wf + (size_t)d * 8);
    f32x4 w1 = *(const f32x4*)(Wf + (size_t)d * 8 + 4);
    acc[0] += xv * w0[0]; acc[1] += xv * w0[1];
    acc[2] += xv * w0[2]; acc[3] += xv * w0[3];
    acc[4] += xv * w1[0]; acc[5] += xv * w1[1];
    acc[6] += xv * w1[2]; acc[7] += xv * w1[3];
  }
#pragma unroll
  for (int n = 0; n < 8; ++n) {
#pragma unroll
    for (int m = 1; m < 64; m <<= 1) acc[n] += __shfl_xor(acc[n], m, 64);
  }
  if (lane == 0) {
#pragma unroll
    for (int n = 0; n < 8; ++n)
      fbuf[(size_t)wid * 8 + n] = sigmoidf_fast(acc[n] + bfv[n]);
  }
}

// ---------------- transpose + cast: (R,C) f32 -> (C,R) bf16 ----------------
__global__ void tcast_kernel(const float* __restrict__ in,
                             unsigned short* __restrict__ out, int R, int C) {
  int i = blockIdx.x * blockDim.x + threadIdx.x;
  if (i >= R * C) return;
  int r = i / C, c = i % C;
  out[(size_t)c * R + r] = f2bf(in[i]);
}

// ---------------- transpose + split cast, all 3 weights; 16B vectorized writes ----------------
// Thread handles 8 consecutive output r's: reads coalesced (lane-consecutive c at
// each j), writes one 16B hi + one 16B lo run (vs 2B scattered before).
__global__ void tcast_split3_kernel(const float* __restrict__ Wq,
                                    const float* __restrict__ Wk,
                                    const float* __restrict__ Wv,
                                    unsigned short* __restrict__ oh,
                                    unsigned short* __restrict__ ol) {
  int i = blockIdx.x * 256 + threadIdx.x;          // 0..65535
  int z = blockIdx.y;
  const float* in = (z == 0) ? Wq : (z == 1) ? Wk : Wv;
  int c = i & 511, r8 = i >> 9;                    // c in [0,512), r8 in [0,128)
  u16x8 h, l;
#pragma unroll
  for (int j = 0; j < 8; ++j) {
    float v = in[(size_t)(r8 * 8 + j) * 512 + c];
    unsigned short hb = f2bf(v);
    h[j] = hb;
    l[j] = f2bf(v - bf2f(hb));
  }
  size_t o = (size_t)z * 524288 + (size_t)c * 1024 + r8 * 8;
  *(u16x8*)(oh + o) = h;
  *(u16x8*)(ol + o) = l;
}

// ---------------- causal depthwise conv (KC=4) + SiLU, all 3 tensors ----------------
__global__ void conv_silu_kernel(const float* __restrict__ pre,
                                 const float* __restrict__ cwq,
                                 const float* __restrict__ cwk,
                                 const float* __restrict__ cwv,
                                 float* __restrict__ outb) {
  int i = blockIdx.x * blockDim.x + threadIdx.x;  // B*L*512
  int which = blockIdx.y;
  const float* cw = (which == 0) ? cwq : (which == 1) ? cwk : cwv;
  const float* p = pre + (size_t)which * 2097152 + i;
  int c = i & 511;
  int l = (i >> 9) & 1023;
  float w0 = cw[c * 4 + 0], w1 = cw[c * 4 + 1], w2 = cw[c * 4 + 2], w3 = cw[c * 4 + 3];
  float acc = w3 * p[0];
  if (l >= 1) acc += w2 * p[-512];
  if (l >= 2) acc += w1 * p[-1024];
  if (l >= 3) acc += w0 * p[-1536];
  outb[(size_t)which * 2097152 + i] = acc * sigmoidf_fast(acc);
}

// ---------------- q/k/v pre-activation GEMM, one dispatch ----------------
// z = 0: q, plain 1-term bf16.  z = 1,2: k/v, split-bf16 3-term.
__global__ __launch_bounds__(256) void gemm_qkv_kernel(
    const unsigned short* __restrict__ Ah, const unsigned short* __restrict__ Al,
    const unsigned short* __restrict__ Bth, const unsigned short* __restrict__ Btl,
    float* __restrict__ C) {
  __shared__ unsigned short AshH[128][40];
  __shared__ unsigned short AshL[128][40];
  __shared__ unsigned short BshH[128][40];
  __shared__ unsigned short BshL[128][40];
  const int tid = threadIdx.x;
  const int wave = tid >> 6, lane = tid & 63;
  const int g = lane >> 4, lr = lane & 15;
  const int m0 = blockIdx.x * 128, n0 = blockIdx.y * 128;
  const int z = blockIdx.z;
  const bool split = (z != 0);
  const int Kd = 1024;
  const unsigned short* Bzh = Bth + (size_t)z * 524288;
  const unsigned short* Bzl = Btl + (size_t)z * 524288;
  float* Cz = C + (size_t)z * 2097152;
  const int wm = (wave >> 1) * 64, wn = (wave & 1) * 64;

  f32x4 acc[4][4];
#pragma unroll
  for (int a = 0; a < 4; ++a)
#pragma unroll
    for (int bq = 0; bq < 4; ++bq) acc[a][bq] = (f32x4){0.f, 0.f, 0.f, 0.f};

  for (int k0 = 0; k0 < Kd; k0 += 32) {
#pragma unroll
    for (int it = 0; it < 2; ++it) {
      int cch = tid + 256 * it;
      int r = cch >> 2, cc = cch & 3;
      size_t ao = (size_t)(m0 + r) * Kd + k0 + cc * 8;
      size_t bo = (size_t)(n0 + r) * Kd + k0 + cc * 8;
      *(i32x4*)&AshH[r][cc * 8] = *(const i32x4*)(Ah + ao);
      *(i32x4*)&BshH[r][cc * 8] = *(const i32x4*)(Bzh + bo);
      if (split) {
        *(i32x4*)&AshL[r][cc * 8] = *(const i32x4*)(Al + ao);
        *(i32x4*)&BshL[r][cc * 8] = *(const i32x4*)(Bzl + bo);
      }
    }
    __syncthreads();
    short8 afh[4], bfh[4];
#pragma unroll
    for (int mt = 0; mt < 4; ++mt) afh[mt] = *(const short8*)&AshH[wm + mt * 16 + lr][g * 8];
#pragma unroll
    for (int nt = 0; nt < 4; ++nt) bfh[nt] = *(const short8*)&BshH[wn + nt * 16 + lr][g * 8];
    if (split) {
      short8 afl[4], bfl[4];
#pragma unroll
      for (int mt = 0; mt < 4; ++mt) afl[mt] = *(const short8*)&AshL[wm + mt * 16 + lr][g * 8];
#pragma unroll
      for (int nt = 0; nt < 4; ++nt) bfl[nt] = *(const short8*)&BshL[wn + nt * 16 + lr][g * 8];
#pragma unroll
      for (int mt = 0; mt < 4; ++mt)
#pragma unroll
        for (int nt = 0; nt < 4; ++nt) {
          f32x4 a = acc[mt][nt];
          a = __builtin_amdgcn_mfma_f32_16x16x32_bf16(afl[mt], bfh[nt], a, 0, 0, 0);
          a = __builtin_amdgcn_mfma_f32_16x16x32_bf16(afh[mt], bfl[nt], a, 0, 0, 0);
          a = __builtin_amdgcn_mfma_f32_16x16x32_bf16(afh[mt], bfh[nt], a, 0, 0, 0);
          acc[mt][nt] = a;
        }
    } else {
#pragma unroll
      for (int mt = 0; mt < 4; ++mt)
#pragma unroll
        for (int nt = 0; nt < 4; ++nt)
          acc[mt][nt] = __builtin_amdgcn_mfma_f32_16x16x32_bf16(afh[mt], bfh[nt], acc[mt][nt], 0, 0, 0);
    }
    __syncthreads();
  }
#pragma unroll
  for (int mt = 0; mt < 4; ++mt)
#pragma unroll
    for (int nt = 0; nt < 4; ++nt)
#pragma unroll
      for (int r = 0; r < 4; ++r) {
        int m = m0 + wm + mt * 16 + g * 4 + r;
        int n = n0 + wn + nt * 16 + lr;
        Cz[(size_t)m * 512 + n] = acc[mt][nt][r];
      }
}

// ---------------- Wo projection GEMM with fused 4-partial y sum ----------------
__global__ __launch_bounds__(256) void gemm_wo_kernel(
    const unsigned short* __restrict__ yp, const unsigned short* __restrict__ Bt,
    float* __restrict__ C) {
  __shared__ unsigned short Ash[128][40];
  __shared__ unsigned short Bsh[128][40];
  const int tid = threadIdx.x;
  const int wave = tid >> 6, lane = tid & 63;
  const int g = lane >> 4, lr = lane & 15;
  const int m0 = blockIdx.x * 128, n0 = blockIdx.y * 128;
  const int Kd = 512, Nd = 1024;
  const int wm = (wave >> 1) * 64, wn = (wave & 1) * 64;

  f32x4 acc[4][4];
#pragma unroll
  for (int a = 0; a < 4; ++a)
#pragma unroll
    for (int bq = 0; bq < 4; ++bq) acc[a][bq] = (f32x4){0.f, 0.f, 0.f, 0.f};

  for (int k0 = 0; k0 < Kd; k0 += 32) {
#pragma unroll
    for (int it = 0; it < 2; ++it) {
      int cch = tid + 256 * it;
      int r = cch >> 2, cc = cch & 3;
      size_t ao = (size_t)(m0 + r) * Kd + k0 + cc * 8;
      u16x4 p0a = *(const u16x4*)(yp + ao);
      u16x4 p0b = *(const u16x4*)(yp + ao + 4);
      u16x4 p1a = *(const u16x4*)(yp + 2097152 + ao);
      u16x4 p1b = *(const u16x4*)(yp + 2097152 + ao + 4);
      u16x4 p2a = *(const u16x4*)(yp + 2 * 2097152 + ao);
      u16x4 p2b = *(const u16x4*)(yp + 2 * 2097152 + ao + 4);
      u16x4 p3a = *(const u16x4*)(yp + 3 * 2097152 + ao);
      u16x4 p3b = *(const u16x4*)(yp + 3 * 2097152 + ao + 4);
      u16x4 sa, sb2;
#pragma unroll
      for (int j = 0; j < 4; ++j) {
        sa[j]  = f2bf(bf2f(p0a[j]) + bf2f(p1a[j]) + bf2f(p2a[j]) + bf2f(p3a[j]));
        sb2[j] = f2bf(bf2f(p0b[j]) + bf2f(p1b[j]) + bf2f(p2b[j]) + bf2f(p3b[j]));
      }
      *(u16x4*)&Ash[r][cc * 8] = sa;
      *(u16x4*)&Ash[r][cc * 8 + 4] = sb2;
      *(i32x4*)&Bsh[r][cc * 8] = *(const i32x4*)(Bt + (size_t)(n0 + r) * Kd + k0 + cc * 8);
    }
    __syncthreads();
    short8 af[4], bfr[4];
#pragma unroll
    for (int mt = 0; mt < 4; ++mt) af[mt] = *(const short8*)&Ash[wm + mt * 16 + lr][g * 8];
#pragma unroll
    for (int nt = 0; nt < 4; ++nt) bfr[nt] = *(const short8*)&Bsh[wn + nt * 16 + lr][g * 8];
#pragma unroll
    for (int mt = 0; mt < 4; ++mt)
#pragma unroll
      for (int nt = 0; nt < 4; ++nt)
        acc[mt][nt] = __builtin_amdgcn_mfma_f32_16x16x32_bf16(af[mt], bfr[nt], acc[mt][nt], 0, 0, 0);
    __syncthreads();
  }
#pragma unroll
  for (int mt = 0; mt < 4; ++mt)
#pragma unroll
    for (int nt = 0; nt < 4; ++nt)
#pragma unroll
      for (int r = 0; r < 4; ++r) {
        int m = m0 + wm + mt * 16 + g * 4 + r;
        int n = n0 + wn + nt * 16 + lr;
        C[(size_t)m * Nd + n] = acc[mt][nt][r];
      }
}

// ---------------- recurrent scan: k-slice split (r11-verified) ----------------
// r17 delta: all step/chunk barriers use lds_barrier() (lgkmcnt-only drain +
// raw s_barrier) -- skips the vmcnt(0) drain __syncthreads adds, which forced
// chunk-staging global loads / ypart stores to retire inside step barriers.
// Slice H planes (ping-pong): row lr at byte lr*128, elem v at (2v)^((lr&7)<<4).
__global__ __launch_bounds__(256) void scan_kernel(
    const float* __restrict__ qbuf, const float* __restrict__ kbuf,
    const float* __restrict__ vbuf, const float* __restrict__ fbuf,
    const float* __restrict__ W, unsigned short* __restrict__ ypart,
    float* __restrict__ Hout) {
  const int tid = threadIdx.x;
  const int wave = tid >> 6, lane = tid & 63;
  const int g = lane >> 4, lr = lane & 15;
  const int bz = blockIdx.x;
  const int chain = bz >> 2, ks = bz & 3;
  const int b = chain >> 3, n = chain & 7;
  const int swz = (lr & 7) << 4;

  __shared__ unsigned short Hh[2][1024];   // 16x64 bf16 hi, ping-pong
  __shared__ unsigned short Hl[2][1024];   // lo planes
  __shared__ float stage[2][16][192];      // 24 KB
  __shared__ float fs[2][16];
  __shared__ float yst[16][64];            // 4 KB

  for (int i = tid; i < 512; i += 256) {
    ((unsigned*)Hh[0])[i] = 0u;
    ((unsigned*)Hl[0])[i] = 0u;
  }

  // W^T split hi/lo fragments: A[m=lr][k-chunk], m = w = 16*wave + lr
  const float* Wn = W + (size_t)n * 4096;
  short8 Af[2], Alw[2];
#pragma unroll
  for (int s = 0; s < 2; ++s) {
    int wcol = wave * 16 + lr;
    short8 ah, al;
#pragma unroll
    for (int j = 0; j < 8; ++j) {
      float wv = Wn[(size_t)(s * 32 + g * 8 + j) * 64 + wcol];
      unsigned short hb = f2bf(wv);
      ah[j] = (short)hb;
      al[j] = (short)f2bf(wv - bf2f(hb));
    }
    Af[s] = ah; Alw[s] = al;
  }

  // chunk staging: 16 steps x 192 floats = 768 f32x4 by 256 threads (3 each)
  auto stage_chunk = [&](int c, int buf) {
#pragma unroll
    for (int i = 0; i < 3; ++i) {
      int fi = tid + i * 256;
      int st = fi / 48, un = fi - st * 48;
      const float* basep = (un < 16) ? qbuf : (un < 32) ? kbuf : vbuf;
      f32x4 val = *(const f32x4*)(basep + (size_t)(b * 1024 + c * 16 + st) * 512 +
                                  n * 64 + (un & 15) * 4);
      *(f32x4*)&stage[buf][st][un * 4] = val;
    }
    if (tid < 16) fs[buf][tid] = fbuf[(size_t)(b * 1024 + c * 16 + tid) * 8 + n];
  };

  f32x4 HA = (f32x4){0.f, 0.f, 0.f, 0.f};  // H[ks*16+lr][w=16*wave+4g+r], f32 master
  int sb = 0, pp = 0;

  stage_chunk(0, 0);
  lds_barrier();

  const f32x4 zf = (f32x4){0.f, 0.f, 0.f, 0.f};
  const int bo0 = (16 * g) ^ swz;               // B-frag chunk 0
  const int bo1 = (64 + 16 * g) ^ swz;          // chunk 1
  const int wo = (32 * wave + 8 * g) ^ swz;     // H-write
  const float K2L2E = 2.885390081777927f;       // 2*log2(e)
  const int kg = ks * 16 + lr;                  // global k row of this lane

  for (int c = 0; c < 64; ++c) {
    if (c < 63) stage_chunk(c + 1, sb ^ 1);
    for (int tl = 0; tl < 16; ++tl) {
      const float* srow = &stage[sb][tl][0];

      // B-frags of H_t slice from plane pp
      const char* hrh = (const char*)(Hh[pp] + lr * 64);
      const char* hrl = (const char*)(Hl[pp] + lr * 64);
      short8 Bh0 = *(const short8*)(hrh + bo0);
      short8 Bh1 = *(const short8*)(hrh + bo1);
      short8 Bl0 = *(const short8*)(hrl + bo0);
      short8 Bl1 = *(const short8*)(hrl + bo1);

      // 6 MFMAs: 3-term split, 2 independent chains of 3
      f32x4 cX = __builtin_amdgcn_mfma_f32_16x16x32_bf16(Alw[0], Bh0, zf, 0, 0, 0);
      f32x4 cY = __builtin_amdgcn_mfma_f32_16x16x32_bf16(Alw[1], Bh1, zf, 0, 0, 0);
      cX = __builtin_amdgcn_mfma_f32_16x16x32_bf16(Af[0], Bl0, cX, 0, 0, 0);
      cY = __builtin_amdgcn_mfma_f32_16x16x32_bf16(Af[1], Bl1, cY, 0, 0, 0);
      cX = __builtin_amdgcn_mfma_f32_16x16x32_bf16(Af[0], Bh0, cX, 0, 0, 0);
      cY = __builtin_amdgcn_mfma_f32_16x16x32_bf16(Af[1], Bh1, cY, 0, 0, 0);

      float kval = srow[64 + kg];
      f32x4 vv = *(const f32x4*)(srow + 128 + wave * 16 + 4 * g);
      float fc = fs[sb][tl];
      f32x4 a0 = cX + cY;

      // tanh (exp2-fused, overflow-safe) + gate blend -> H_{t+1} (f32, exact)
#pragma unroll
      for (int r = 0; r < 4; ++r) {
        float arg = fmaf(kval, vv[r], a0[r]);
        float cd = fmaf(-2.f, __builtin_amdgcn_rcpf(1.f + __builtin_amdgcn_exp2f(arg * K2L2E)), 1.f);
        HA[r] = fmaf(fc, HA[r] - cd, cd);
      }

      // pack (cvt_pk) and write H_{t+1} to plane pp^1 FIRST (retires under y-VALU)
      {
        char* hwh = (char*)(Hh[pp ^ 1] + lr * 64);
        char* hwl = (char*)(Hl[pp ^ 1] + lr * 64);
        unsigned ph0 = cvt_pk_bf16(HA[0], HA[1]);
        unsigned ph1 = cvt_pk_bf16(HA[2], HA[3]);
        float r0 = HA[0] - __builtin_bit_cast(float, ph0 << 16);
        float r1 = HA[1] - __builtin_bit_cast(float, ph0 & 0xFFFF0000u);
        float r2 = HA[2] - __builtin_bit_cast(float, ph1 << 16);
        float r3 = HA[3] - __builtin_bit_cast(float, ph1 & 0xFFFF0000u);
        *(u32x2*)(hwh + wo) = (u32x2){ph0, ph1};
        *(u32x2*)(hwl + wo) = (u32x2){cvt_pk_bf16(r0, r1), cvt_pk_bf16(r2, r3)};
      }

      // y slice-partials: DPP row-sum over the 16 k-lanes (VALU covers the writes)
      {
        float qs = srow[kg];
        float y0 = row_sum16(qs * HA[0]);
        float y1 = row_sum16(qs * HA[1]);
        float y2 = row_sum16(qs * HA[2]);
        float y3 = row_sum16(qs * HA[3]);
        if (lr == 15)
          *(f32x4*)&yst[tl][wave * 16 + 4 * g] = (f32x4){y0, y1, y2, y3};
      }

      lds_barrier();   // LDS-only: plane pp^1 + yst visible, no vmcnt drain
      pp ^= 1;
    }

    // flush y slice-partials for this chunk (bf16), coalesced
    for (int i = tid; i < 1024; i += 256) {
      int tl2 = i >> 6, w = i & 63;
      ypart[(size_t)ks * 2097152 +
            (size_t)(b * 1024 + c * 16 + tl2) * 512 + n * 64 + w] = f2bf(yst[tl2][w]);
    }
    lds_barrier();   // protect yst reuse by next chunk (reads drained via lgkm)
    sb ^= 1;
  }

  // H_final (f32 master): this slice owns rows ks*16..ks*16+16
  float* Ho = Hout + (size_t)(b * 8 + n) * 4096;
  *(f32x4*)&Ho[(size_t)kg * 64 + wave * 16 + g * 4] = HA;
}

// ---------------- launch ----------------
extern "C" void kernel_launch(void* const* d_in, const int* in_sizes, int n_in,
                              void* d_out, int out_size, void* d_ws, size_t ws_size,
                              hipStream_t stream) {
  const float* x   = (const float*)d_in[0];
  const float* Wq  = (const float*)d_in[1];
  const float* Wk  = (const float*)d_in[2];
  const float* Wv  = (const float*)d_in[3];
  const float* Wf  = (const float*)d_in[4];
  const float* bfv = (const float*)d_in[5];
  const float* cwq = (const float*)d_in[6];
  const float* cwk = (const float*)d_in[7];
  const float* cwv = (const float*)d_in[8];
  const float* W   = (const float*)d_in[9];
  const float* Wo  = (const float*)d_in[10];
  float* outp = (float*)d_out;

  char* ws = (char*)d_ws;
  size_t off = 0;
  auto alloc = [&](size_t bytes) {
    char* pp = ws + off;
    off = (off + bytes + 255) & ~(size_t)255;
    return pp;
  };
  unsigned short* xbh  = (unsigned short*)alloc((size_t)4194304 * 2);
  unsigned short* xbl  = (unsigned short*)alloc((size_t)4194304 * 2);
  unsigned short* wtbh = (unsigned short*)alloc((size_t)3 * 524288 * 2);
  unsigned short* wtbl = (unsigned short*)alloc((size_t)3 * 524288 * 2);
  float* pre  = (float*)alloc((size_t)3 * 2097152 * 4);   // aliased: y partials
  float* qkv  = (float*)alloc((size_t)3 * 2097152 * 4);
  float* fbuf = (float*)alloc((size_t)32768 * 4);
  unsigned short* wot = (unsigned short*)alloc((size_t)524288 * 2);
  unsigned short* ypart = (unsigned short*)pre;  // pre is dead after conv_silu

  // prep: cast x (hi/lo) + f gate, fused
  prep_kernel<<<1024, 256, 0, stream>>>(x, Wf, bfv, xbh, xbl, fbuf);
  // weight transposes (split hi/lo), vectorized writes
  dim3 gt(256, 3, 1);
  tcast_split3_kernel<<<gt, 256, 0, stream>>>(Wq, Wk, Wv, wtbh, wtbl);
  // q/k/v pre-activations in ONE dispatch (z=0 plain, z=1,2 split)
  dim3 g1(32, 4, 3);
  gemm_qkv_kernel<<<g1, 256, 0, stream>>>(xbh, xbl, wtbh, wtbl, pre);
  // conv + silu (all three in one launch); pre is dead afterwards
  dim3 gc(8192, 3, 1);
  conv_silu_kernel<<<gc, 256, 0, stream>>>(pre, cwq, cwk, cwv, qkv);
  // recurrent scan: 128 blocks (32 chains x 4 k-slices) x 256 threads
  scan_kernel<<<128, 256, 0, stream>>>(qkv, qkv + 2097152, qkv + 2 * 2097152, fbuf, W,
                                       ypart, outp + 4194304);
  // output projection with fused 4-partial y sum
  tcast_kernel<<<2048, 256, 0, stream>>>(Wo, wot, 512, 1024);
  dim3 g2(32, 8, 1);
  gemm_wo_kernel<<<g2, 256, 0, stream>>>(ypart, wot, outp);
}